// Round 12
// baseline (887.775 us; speedup 1.0000x reference)
//
#include <hip/hip_runtime.h>
#include <hip/hip_bf16.h>
#include <math.h>

// 5 graph nodes:
//   memset(bar)
//   premega <<<1568,256>>> __launch_bounds__(256,7): fc|ct0|ct1|ct2|convf|cost|prep
//           (18KB pool -> 7 blocks/CU co-resident = 76% occupancy; R9-proven bodies)
//   sag     <<<1,512>>>  single-wave scan (R6-proven 226us) + 7 L2-warm waves
//   p_k     <<<512,256>>> plan recovery + Cout
//   kl_k    <<<1,512>>>
// Barrier: two-level relaxed-spin (R8-validated: agent-ACQUIRE spins buffer_inv the L2).

typedef float vf4 __attribute__((ext_vector_type(4)));

#define NBPRE 1568

// ---------------- two-level grid barrier ----------------
// bar[0]=master, bar[32]=gen, bar[64+g*32]=sub counters (32 groups)
__device__ __forceinline__ void gridbar2(unsigned* bar, unsigned nb) {
  __syncthreads();
  if (threadIdx.x == 0) {
    unsigned* gen = bar + 32;
    unsigned g = __hip_atomic_load(gen, __ATOMIC_RELAXED, __HIP_MEMORY_SCOPE_AGENT);
    __threadfence();   // release
    unsigned grp = (unsigned)blockIdx.x & 31u;
    unsigned* sub = bar + 64 + grp * 32;
    unsigned per = nb >> 5;
    unsigned a = __hip_atomic_fetch_add(sub, 1u, __ATOMIC_RELAXED, __HIP_MEMORY_SCOPE_AGENT);
    if (a == per - 1u) {
      __hip_atomic_store(sub, 0u, __ATOMIC_RELAXED, __HIP_MEMORY_SCOPE_AGENT);
      unsigned m = __hip_atomic_fetch_add(bar, 1u, __ATOMIC_RELAXED, __HIP_MEMORY_SCOPE_AGENT);
      if (m == 31u) {
        __hip_atomic_store(bar, 0u, __ATOMIC_RELAXED, __HIP_MEMORY_SCOPE_AGENT);
        __hip_atomic_store(gen, g + 1u, __ATOMIC_RELEASE, __HIP_MEMORY_SCOPE_AGENT);
      } else {
        while (__hip_atomic_load(gen, __ATOMIC_RELAXED, __HIP_MEMORY_SCOPE_AGENT) == g)
          __builtin_amdgcn_s_sleep(8);
      }
    } else {
      while (__hip_atomic_load(gen, __ATOMIC_RELAXED, __HIP_MEMORY_SCOPE_AGENT) == g)
        __builtin_amdgcn_s_sleep(8);
    }
    __threadfence();   // acquire (once per barrier)
  }
  __syncthreads();
}

// ---------------- cross-lane helpers ----------------
template <int CTRL>
__device__ __forceinline__ float dpp_f(float x) {
  return __int_as_float(__builtin_amdgcn_update_dpp(0, __float_as_int(x), CTRL, 0xF, 0xF, true));
}
__device__ __forceinline__ float rdl(float v, int l) {
  return __int_as_float(__builtin_amdgcn_readlane(__float_as_int(v), l));
}
__device__ __forceinline__ float wsum64_l63(float v) {
  v += dpp_f<0xB1>(v);
  v += dpp_f<0x4E>(v);
  v += dpp_f<0x141>(v);
  v += dpp_f<0x140>(v);
  v += dpp_f<0x142>(v);
  v += dpp_f<0x143>(v);
  return rdl(v, 63);
}
__device__ __forceinline__ float wmax64_l63(float v) {
  v = fmaxf(v, dpp_f<0xB1>(v));
  v = fmaxf(v, dpp_f<0x4E>(v));
  v = fmaxf(v, dpp_f<0x141>(v));
  v = fmaxf(v, dpp_f<0x140>(v));
  v = fmaxf(v, dpp_f<0x142>(v));
  v = fmaxf(v, dpp_f<0x143>(v));
  return rdl(v, 63);
}

// ---------------- ConvT quad-gather (LDS weights, NHALF staging) ----------------
#define TAPF(T, P, XV) { \
  const float4* w4_ = reinterpret_cast<const float4*>(&wt[((T) * CH + ci) * 8]); \
  float4 wa_ = w4_[0], wb_ = w4_[1]; \
  acc[P][0] = fmaf(XV, wa_.x, acc[P][0]); \
  acc[P][1] = fmaf(XV, wa_.y, acc[P][1]); \
  acc[P][2] = fmaf(XV, wa_.z, acc[P][2]); \
  acc[P][3] = fmaf(XV, wa_.w, acc[P][3]); \
  acc[P][4] = fmaf(XV, wb_.x, acc[P][4]); \
  acc[P][5] = fmaf(XV, wb_.y, acc[P][5]); \
  acc[P][6] = fmaf(XV, wb_.z, acc[P][6]); \
  acc[P][7] = fmaf(XV, wb_.w, acc[P][7]); }

template <int CIN, int COUT, int HIN, int HOUT, int NHALF>
__device__ void convt_body(const float* __restrict__ x, const float* __restrict__ w,
                           const float* __restrict__ bias, float* __restrict__ y,
                           int bx, int g8b, int tid, float* wt) {
  constexpr int CH = CIN / NHALF;            // pool usage: 9*CH*8 <= 4608 floats
  constexpr bool FULL = (HOUT == 2 * HIN);
  constexpr int QP = HIN * HIN;
  const int g8 = g8b * 8;

  int q = bx * 256 + tid;
  int n = q / QP;
  int pq = q % QP;
  int a = pq / HIN, b = pq % HIN;
  const bool oka = (a + 1 < HIN), okb = (b + 1 < HIN);

  float acc[4][8];
#pragma unroll
  for (int p = 0; p < 4; ++p)
#pragma unroll
    for (int c = 0; c < 8; ++c) acc[p][c] = 0.f;

  for (int h = 0; h < NHALF; ++h) {
    __syncthreads();
    for (int e = tid; e < 9 * CH * 8; e += 256) {
      int cl = e & 7;
      int rest = e >> 3;
      int ci = rest & (CH - 1);
      int t = rest / CH;
      wt[e] = w[((size_t)(h * CH + ci) * COUT + g8 + cl) * 9 + t];
    }
    __syncthreads();
    const float* xim = x + ((size_t)n * CIN + h * CH) * QP + a * HIN + b;
    for (int ci = 0; ci < CH; ++ci) {
      const float* xc = xim + ci * QP;
      float x00 = xc[0];
      float x01 = okb ? xc[1] : 0.f;
      float x10 = oka ? xc[HIN] : 0.f;
      float x11 = (oka && okb) ? xc[HIN + 1] : 0.f;
      TAPF(4, 0, x00)
      TAPF(3, 1, x01) TAPF(5, 1, x00)
      TAPF(1, 2, x10) TAPF(7, 2, x00)
      TAPF(0, 3, x11) TAPF(2, 3, x10) TAPF(6, 3, x01) TAPF(8, 3, x00)
    }
  }

  int oh0 = 2 * a, ow0 = 2 * b;
  bool vh = FULL || (oh0 + 1 < HOUT);
  bool vw = FULL || (ow0 + 1 < HOUT);
#pragma unroll
  for (int c = 0; c < 8; ++c) {
    float bv = bias[g8 + c];
    float o00 = fmaxf(acc[0][c] + bv, 0.f);
    float o01 = fmaxf(acc[1][c] + bv, 0.f);
    float o10 = fmaxf(acc[2][c] + bv, 0.f);
    float o11 = fmaxf(acc[3][c] + bv, 0.f);
    float* yb = y + (((size_t)n * COUT + g8 + c) * HOUT + oh0) * (size_t)HOUT + ow0;
    if (FULL) {
      *(float2*)yb = make_float2(o00, o01);
      *(float2*)(yb + HOUT) = make_float2(o10, o11);
    } else {
      yb[0] = o00;
      if (vw) yb[1] = o01;
      if (vh) yb[HOUT] = o10;
      if (vh && vw) yb[HOUT + 1] = o11;
    }
  }
}

// ---------------- premega: fc | ct0 | ct1 | ct2 | convf | cost | prep ----------------
__global__ __launch_bounds__(256, 7) void premega_k(
    const float* __restrict__ x, const float* __restrict__ z,
    const float* __restrict__ fc_w, const float* __restrict__ fc_b,
    const float* __restrict__ ct0_w, const float* __restrict__ ct0_b,
    const float* __restrict__ ct1_w, const float* __restrict__ ct1_b,
    const float* __restrict__ fct_w, const float* __restrict__ fct_b,
    const float* __restrict__ conv_w, const float* __restrict__ conv_b,
    float* h0, float* h1, float* h2, float* h3,
    float* logit, float* sp, float* stored,
    unsigned* bar) {
  __shared__ float pool[4608];   // 18 KB -> 7 blocks/CU for 1568 blocks (126KB/CU)
  const int tid = threadIdx.x;
  const int bid = blockIdx.x;
  float* Craw = h0;   // aliases h0 (dead after ct0 reads it in P1)
  float* D2 = h1;     // aliases h1 (dead after ct1)

  // ---- P0: zero stored + fc (1024 vb) ----
  {
    int p = bid * 256 + tid;
    if (p < 262144) stored[p] = 0.f;
  }
  if (bid < 1024) {
    int n = bid >> 1;
    int c0 = ((bid & 1) << 10) + tid * 4;
    const float* zr = z + n * 64;
    float4 acc = *(const float4*)&fc_b[c0];
#pragma unroll
    for (int k = 0; k < 64; ++k) {
      float zk = zr[k];
      float4 wv = *(const float4*)&fc_w[k * 2048 + c0];
      acc.x = fmaf(zk, wv.x, acc.x);
      acc.y = fmaf(zk, wv.y, acc.y);
      acc.z = fmaf(zk, wv.z, acc.z);
      acc.w = fmaf(zk, wv.w, acc.w);
    }
    acc.x = fmaxf(acc.x, 0.f); acc.y = fmaxf(acc.y, 0.f);
    acc.z = fmaxf(acc.z, 0.f); acc.w = fmaxf(acc.w, 0.f);
    *(float4*)&h0[n * 2048 + c0] = acc;
  }
  gridbar2(bar, NBPRE);

  // ---- P1: ct0 128->64, 4->7 (256 vb: 32 pos x 8 grp; weights in 2 halves) ----
  if (bid < 256)
    convt_body<128, 64, 4, 7, 2>(h0, ct0_w, ct0_b, h1, bid & 31, bid >> 5, tid, pool);
  gridbar2(bar, NBPRE);

  // ---- P2: ct1 64->32, 7->14 (392 vb: 98 pos x 4 grp) ----
  if (bid < 392)
    convt_body<64, 32, 7, 14, 1>(h1, ct1_w, ct1_b, h2, bid % 98, bid / 98, tid, pool);
  gridbar2(bar, NBPRE);

  // ---- P3: ct2 32->32, 14->28 (1568 vb: 392 pos x 4 grp) ----
  convt_body<32, 32, 14, 28, 1>(h2, fct_w, fct_b, h3, bid % 392, bid / 392, tid, pool);
  gridbar2(bar, NBPRE);

  // ---- P4: conv_final 32->1 (1568 vb) ----
  {
    __syncthreads();
    if (tid < 256) pool[tid] = conv_w[tid];
    if (tid < 32) pool[256 + tid] = conv_w[256 + tid];
    __syncthreads();
    int gid = bid * 256 + tid;
    int ow = gid % 28;
    int t1 = gid / 28;
    int oh = t1 % 28;
    int n = t1 / 28;
    bool b0 = oh > 0, b2 = oh < 27, w0 = ow > 0, w2 = ow < 27;
    const float* xb = h3 + (size_t)n * 32 * 784 + (oh - 1) * 28 + (ow - 1);
    float acc = conv_b[0];
    for (int ci = 0; ci < 32; ++ci) {
      const float* xc = xb + ci * 784;
      const float* wc = &pool[ci * 9];
      if (b0 && w0) acc = fmaf(xc[0], wc[0], acc);
      if (b0)       acc = fmaf(xc[1], wc[1], acc);
      if (b0 && w2) acc = fmaf(xc[2], wc[2], acc);
      if (w0)       acc = fmaf(xc[28], wc[3], acc);
                    acc = fmaf(xc[29], wc[4], acc);
      if (w2)       acc = fmaf(xc[30], wc[5], acc);
      if (b2 && w0) acc = fmaf(xc[56], wc[6], acc);
      if (b2)       acc = fmaf(xc[57], wc[7], acc);
      if (b2 && w2) acc = fmaf(xc[58], wc[8], acc);
    }
    logit[gid] = acc;
  }
  gridbar2(bar, NBPRE);

  // ---- P5: cost GEMM 32x64 + fused softplus (128 vb) ----
  if (bid < 128) {
    float* Xs = pool;            // [16][36]
    float* Ls = pool + 576;      // [16][68]
    int i0 = (bid >> 3) * 32, j0 = (bid & 7) * 64;
    int lrow = tid >> 2;
    int lq = tid & 3;
    int xrow = tid & 31;
    int xq = (tid >> 5) & 3;
    bool doX = tid < 128;
    bool doSP = (i0 == 0);
    int tx = tid & 15, ty = tid >> 4;
    float acc[2][4] = {};
    float spacc = 0.f;
    for (int k0 = 0; k0 < 784; k0 += 16) {
      float4 lv = *(const float4*)&logit[(size_t)(j0 + lrow) * 784 + k0 + lq * 4];
      float4 xv = {0.f, 0.f, 0.f, 0.f};
      if (doX) xv = *(const float4*)&x[(size_t)(i0 + xrow) * 784 + k0 + xq * 4];
      __syncthreads();
      Ls[(lq * 4 + 0) * 68 + lrow] = lv.x; Ls[(lq * 4 + 1) * 68 + lrow] = lv.y;
      Ls[(lq * 4 + 2) * 68 + lrow] = lv.z; Ls[(lq * 4 + 3) * 68 + lrow] = lv.w;
      if (doX) {
        Xs[(xq * 4 + 0) * 36 + xrow] = xv.x; Xs[(xq * 4 + 1) * 36 + xrow] = xv.y;
        Xs[(xq * 4 + 2) * 36 + xrow] = xv.z; Xs[(xq * 4 + 3) * 36 + xrow] = xv.w;
      }
      if (doSP) {
        spacc += fmaxf(lv.x, 0.f) + log1pf(__expf(-fabsf(lv.x)));
        spacc += fmaxf(lv.y, 0.f) + log1pf(__expf(-fabsf(lv.y)));
        spacc += fmaxf(lv.z, 0.f) + log1pf(__expf(-fabsf(lv.z)));
        spacc += fmaxf(lv.w, 0.f) + log1pf(__expf(-fabsf(lv.w)));
      }
      __syncthreads();
#pragma unroll
      for (int k = 0; k < 16; ++k) {
        float2 a = *(const float2*)&Xs[k * 36 + ty * 2];
        float4 bq = *(const float4*)&Ls[k * 68 + tx * 4];
        acc[0][0] = fmaf(a.x, bq.x, acc[0][0]); acc[0][1] = fmaf(a.x, bq.y, acc[0][1]);
        acc[0][2] = fmaf(a.x, bq.z, acc[0][2]); acc[0][3] = fmaf(a.x, bq.w, acc[0][3]);
        acc[1][0] = fmaf(a.y, bq.x, acc[1][0]); acc[1][1] = fmaf(a.y, bq.y, acc[1][1]);
        acc[1][2] = fmaf(a.y, bq.z, acc[1][2]); acc[1][3] = fmaf(a.y, bq.w, acc[1][3]);
      }
    }
#pragma unroll
    for (int r = 0; r < 2; ++r) {
      float4 o = make_float4(acc[r][0], acc[r][1], acc[r][2], acc[r][3]);
      *(float4*)&Craw[(size_t)(i0 + ty * 2 + r) * 512 + j0 + tx * 4] = o;
    }
    if (doSP) {
      float q = spacc;
      q += dpp_f<0xB1>(q);
      q += dpp_f<0x4E>(q);
      if (lq == 0) sp[j0 + lrow] = q;
    }
  }
  gridbar2(bar, NBPRE);

  // ---- P6: prep (rowmax + shifted log2e cost) (512 vb) ----
  if (bid < 512) {
    int i = bid;
    float c0 = Craw[(size_t)i * 512 + tid];
    float c1 = Craw[(size_t)i * 512 + tid + 256];
    float v0 = c0 - sp[tid];
    float v1 = c1 - sp[tid + 256];
    __syncthreads();
    pool[tid] = fmaxf(v0, v1);
    __syncthreads();
    for (int st = 128; st > 0; st >>= 1) {
      if (tid < st) pool[tid] = fmaxf(pool[tid], pool[tid + st]);
      __syncthreads();
    }
    float m = pool[0];
    const float L2E = 1.4426950408889634f;
    D2[(size_t)i * 512 + tid] = (m - v0) * L2E;
    D2[(size_t)i * 512 + tid + 256] = (m - v1) * L2E;
  }
}

// ---------------- SAG scan (single wave, R6-proven; log2e domain, native exp2) ----------------
#define SLD0(ROW) { const float* cp_ = D2 + ((size_t)(unsigned)(ROW) << 9) + jb; \
  s0dA = *(const vf4*)cp_; s0dB = *(const vf4*)(cp_ + 4); \
  const float* tp_ = stored + ((size_t)(unsigned)(ROW) << 9) + jb; \
  s0sA = *(const vf4*)tp_; s0sB = *(const vf4*)(tp_ + 4); }
#define SLD1(ROW) { const float* cp_ = D2 + ((size_t)(unsigned)(ROW) << 9) + jb; \
  s1dA = *(const vf4*)cp_; s1dB = *(const vf4*)(cp_ + 4); \
  const float* tp_ = stored + ((size_t)(unsigned)(ROW) << 9) + jb; \
  s1sA = *(const vf4*)tp_; s1sB = *(const vf4*)(tp_ + 4); }

#define STEP(RR, PFR, DA, DB, SA, SB, LDM, \
             R1,A1,B1, R2,A2,B2, R3,A3,B3, R4,A4,B4, R5,A5,B5, R6,A6,B6, \
             GA, GB) \
{ \
  vf4 d0_ = DA, d1_ = DB, t0_ = SA, t1_ = SB; \
  LDM(PFR); \
  const int r_ = (RR); \
  if (__builtin_expect((r_==(R1)) | (r_==(R2)) | (r_==(R3)) | \
                       (r_==(R4)) | (r_==(R5)) | (r_==(R6)), 0)) { \
    if (r_==(R6)) { t0_ = A6; t1_ = B6; } \
    if (r_==(R5)) { t0_ = A5; t1_ = B5; } \
    if (r_==(R4)) { t0_ = A4; t1_ = B4; } \
    if (r_==(R3)) { t0_ = A3; t1_ = B3; } \
    if (r_==(R2)) { t0_ = A2; t1_ = B2; } \
    if (r_==(R1)) { t0_ = A1; t1_ = B1; } \
  } \
  vf4 u0_ = ssumL - t0_; \
  vf4 u1_ = ssumH - t1_; \
  vf4 a0_ = betaL - d0_; \
  vf4 a1_ = betaH - d1_; \
  vf4 e0_, e1_; \
  e0_.x = __builtin_amdgcn_exp2f(a0_.x); e0_.y = __builtin_amdgcn_exp2f(a0_.y); \
  e0_.z = __builtin_amdgcn_exp2f(a0_.z); e0_.w = __builtin_amdgcn_exp2f(a0_.w); \
  e1_.x = __builtin_amdgcn_exp2f(a1_.x); e1_.y = __builtin_amdgcn_exp2f(a1_.y); \
  e1_.z = __builtin_amdgcn_exp2f(a1_.z); e1_.w = __builtin_amdgcn_exp2f(a1_.w); \
  vf4 es_ = e0_ + e1_; \
  float S_ = wsum64_l63((es_.x + es_.z) + (es_.y + es_.w)); \
  S_ = fmaxf(S_, 1e-35f); \
  float kk_ = C2NL * __builtin_amdgcn_rcpf(S_); \
  vf4 g0_ = e0_ * kk_ + c1l4; \
  vf4 g1_ = e1_ * kk_ + c1l4; \
  ssumL = u0_ + g0_; ssumH = u1_ + g1_; \
  betaL += ssumL; betaH += ssumH; \
  float* wp_ = stored + ((size_t)(unsigned)r_ << 9) + jb; \
  *(vf4*)wp_ = g0_; *(vf4*)(wp_ + 4) = g1_; \
  GA = g0_; GB = g1_; \
}

__global__ void __launch_bounds__(512, 1) sag_k(const float* __restrict__ D2,
                                                const int* __restrict__ idx,
                                                float* __restrict__ stored,
                                                float* __restrict__ beta_out) {
  const int tid = threadIdx.x;
  if (tid >= 64) {
    // waves 1-7: warm D2 + stored into this XCD's L2 while wave 0 scans
    const vf4* c4 = (const vf4*)D2;
    const vf4* s4 = (const vf4*)stored;
    vf4 acc = {0.f, 0.f, 0.f, 0.f};
    for (int p = tid - 64; p < 65536; p += 448) { acc += c4[p]; acc += s4[p]; }
    float accs = acc.x + acc.y + acc.z + acc.w;
    asm volatile("" :: "v"(accs));
    return;
  }

  const int jb = tid * 8;
  const float C2NL = -0.0028177637f;                 // -(1/512)*log2e
  const vf4 c1l4 = {5.503574e-06f, 5.503574e-06f, 5.503574e-06f, 5.503574e-06f};

  vf4 z4 = {0.f, 0.f, 0.f, 0.f};
  vf4 betaL = z4, betaH = z4, ssumL = z4, ssumH = z4;
  vf4 h1A = z4, h1B = z4, h2A = z4, h2B = z4, h3A = z4, h3B = z4;
  vf4 h4A = z4, h4B = z4, h5A = z4, h5B = z4, h6A = z4, h6B = z4;
  int hr1 = -1, hr2 = -1, hr3 = -1, hr4 = -1, hr5 = -1, hr6 = -1;
  float vsh = 0.f;

  int4 ia = *(const int4*)&idx[0];
  int4 ib = *(const int4*)&idx[4];
  int i0 = ia.x, i1 = ia.y, i2 = ia.z, i3 = ia.w;
  int i4 = ib.x, i5 = ib.y, i6 = ib.z, i7 = ib.w;

  vf4 s0dA, s0dB, s0sA, s0sB, s1dA, s1dB, s1sA, s1sB;
  SLD0(i0);
  SLD1(i1);

  vf4 g0a, g0b, g1a, g1b, g2a, g2b, g3a, g3b;
  vf4 g4a, g4b, g5a, g5b, g6a, g6b, g7a, g7b;

  for (int t = 0; t < 1000; t += 8) {
    int tb = (t + 8 < 1000) ? (t + 8) : 992;
    int4 na = *(const int4*)&idx[tb];
    int4 nb = *(const int4*)&idx[tb + 4];

    STEP(i0, i2, s0dA, s0dB, s0sA, s0sB, SLD0,
         hr1,h1A,h1B, hr2,h2A,h2B, hr3,h3A,h3B, hr4,h4A,h4B, hr5,h5A,h5B, hr6,h6A,h6B,
         g0a, g0b)
    STEP(i1, i3, s1dA, s1dB, s1sA, s1sB, SLD1,
         i0,g0a,g0b, hr1,h1A,h1B, hr2,h2A,h2B, hr3,h3A,h3B, hr4,h4A,h4B, hr5,h5A,h5B,
         g1a, g1b)
    STEP(i2, i4, s0dA, s0dB, s0sA, s0sB, SLD0,
         i1,g1a,g1b, i0,g0a,g0b, hr1,h1A,h1B, hr2,h2A,h2B, hr3,h3A,h3B, hr4,h4A,h4B,
         g2a, g2b)
    STEP(i3, i5, s1dA, s1dB, s1sA, s1sB, SLD1,
         i2,g2a,g2b, i1,g1a,g1b, i0,g0a,g0b, hr1,h1A,h1B, hr2,h2A,h2B, hr3,h3A,h3B,
         g3a, g3b)
    STEP(i4, i6, s0dA, s0dB, s0sA, s0sB, SLD0,
         i3,g3a,g3b, i2,g2a,g2b, i1,g1a,g1b, i0,g0a,g0b, hr1,h1A,h1B, hr2,h2A,h2B,
         g4a, g4b)
    STEP(i5, i7, s1dA, s1dB, s1sA, s1sB, SLD1,
         i4,g4a,g4b, i3,g3a,g3b, i2,g2a,g2b, i1,g1a,g1b, i0,g0a,g0b, hr1,h1A,h1B,
         g5a, g5b)
    STEP(i6, na.x, s0dA, s0dB, s0sA, s0sB, SLD0,
         i5,g5a,g5b, i4,g4a,g4b, i3,g3a,g3b, i2,g2a,g2b, i1,g1a,g1b, i0,g0a,g0b,
         g6a, g6b)
    STEP(i7, na.y, s1dA, s1dB, s1sA, s1sB, SLD1,
         i6,g6a,g6b, i5,g5a,g5b, i4,g4a,g4b, i3,g3a,g3b, i2,g2a,g2b, i1,g1a,g1b,
         g7a, g7b)

    {
      vf4 qm;
      qm.x = fmaxf(betaL.x, betaH.x); qm.y = fmaxf(betaL.y, betaH.y);
      qm.z = fmaxf(betaL.z, betaH.z); qm.w = fmaxf(betaL.w, betaH.w);
      float lm = fmaxf(fmaxf(qm.x, qm.y), fmaxf(qm.z, qm.w));
      float dm = wmax64_l63(lm);
      betaL = betaL - dm; betaH = betaH - dm;
      vsh += dm;
    }

    hr1 = i7; h1A = g7a; h1B = g7b;
    hr2 = i6; h2A = g6a; h2B = g6b;
    hr3 = i5; h3A = g5a; h3B = g5b;
    hr4 = i4; h4A = g4a; h4B = g4b;
    hr5 = i3; h5A = g3a; h5B = g3b;
    hr6 = i2; h6A = g2a; h6B = g2b;
    i0 = na.x; i1 = na.y; i2 = na.z; i3 = na.w;
    i4 = nb.x; i5 = nb.y; i6 = nb.z; i7 = nb.w;
  }

  const float LN2 = 0.6931471805599453f;
  vf4 oL = (betaL + vsh) * LN2;
  vf4 oH = (betaH + vsh) * LN2;
  *(vf4*)(beta_out + jb) = oL;
  *(vf4*)(beta_out + jb + 4) = oH;
}

// ---------------- plan recovery + C output + entropy rows ----------------
__global__ void p_k(const float* __restrict__ craw, const float* __restrict__ sp,
                    const float* __restrict__ beta, float* __restrict__ P,
                    float* __restrict__ Cout, float* __restrict__ rowsum) {
  __shared__ float red[256];
  int i = blockIdx.x, tid = threadIdx.x;
  float c0 = craw[(size_t)i * 512 + tid];
  float c1 = craw[(size_t)i * 512 + tid + 256];
  float sp0 = sp[tid], sp1 = sp[tid + 256];
  float u0 = (beta[tid] - sp0) + c0;
  float u1 = (beta[tid + 256] - sp1) + c1;
  Cout[(size_t)i * 512 + tid] = sp0 - c0;
  Cout[(size_t)i * 512 + tid + 256] = sp1 - c1;
  float m = fmaxf(u0, u1);
  red[tid] = m;
  __syncthreads();
  for (int st = 128; st > 0; st >>= 1) {
    if (tid < st) red[tid] = fmaxf(red[tid], red[tid + st]);
    __syncthreads();
  }
  m = red[0];
  __syncthreads();
  float e0 = __expf(u0 - m), e1 = __expf(u1 - m);
  red[tid] = e0 + e1;
  __syncthreads();
  for (int st = 128; st > 0; st >>= 1) {
    if (tid < st) red[tid] += red[tid + st];
    __syncthreads();
  }
  float lse = m + logf(red[0]);
  __syncthreads();
  const float log512 = 6.238324625039508f;
  float p0 = __expf(u0 - lse) * (1.0f / 512.0f);
  float p1 = __expf(u1 - lse) * (1.0f / 512.0f);
  P[(size_t)i * 512 + tid] = p0;
  P[(size_t)i * 512 + tid + 256] = p1;
  float pl = p0 * (u0 - lse - log512) + p1 * (u1 - lse - log512);
  red[tid] = pl;
  __syncthreads();
  for (int st = 128; st > 0; st >>= 1) {
    if (tid < st) red[tid] += red[tid + st];
    __syncthreads();
  }
  if (tid == 0) rowsum[i] = red[0];
}

__global__ void kl_k(const float* __restrict__ rowsum, float* __restrict__ out_kl) {
  __shared__ float red[512];
  int tid = threadIdx.x;
  red[tid] = rowsum[tid];
  __syncthreads();
  for (int st = 256; st > 0; st >>= 1) {
    if (tid < st) red[tid] += red[tid + st];
    __syncthreads();
  }
  if (tid == 0) out_kl[0] = red[0] + 2.0f * 6.238324625039508f;
}

extern "C" void kernel_launch(void* const* d_in, const int* in_sizes, int n_in,
                              void* d_out, int out_size, void* d_ws, size_t ws_size,
                              hipStream_t stream) {
  const float* x = (const float*)d_in[0];
  const float* z = (const float*)d_in[1];
  const float* fc_w = (const float*)d_in[2];
  const float* fc_b = (const float*)d_in[3];
  const float* ct0_w = (const float*)d_in[4];
  const float* ct0_b = (const float*)d_in[5];
  const float* ct1_w = (const float*)d_in[6];
  const float* ct1_b = (const float*)d_in[7];
  const float* fct_w = (const float*)d_in[8];
  const float* fct_b = (const float*)d_in[9];
  const float* conv_w = (const float*)d_in[10];
  const float* conv_b = (const float*)d_in[11];
  const int* idx = (const int*)d_in[12];

  float* out = (float*)d_out;
  float* Pout = out;               // 512*512
  float* Cout = out + 262144;      // 512*512
  float* klout = out + 524288;     // 1

  float* ws = (float*)d_ws;
  float* h0 = ws;                       // 512*2048   (-> Craw after ct0)
  float* h1 = h0 + 1048576;             // 512*64*49  (-> D2 after ct1)
  float* h2 = h1 + 1605632;             // 512*32*196
  float* h3 = h2 + 3211264;             // 512*32*784
  float* logit = h3 + 12845056;         // 512*784
  float* sp = logit + 401408;           // 512
  float* beta = sp + 512;               // 512
  float* stored = beta + 512;           // 512*512
  float* rowsum = stored + 262144;      // 512
  unsigned* bar = (unsigned*)(rowsum + 512);   // 1088+ uints (two-level)
  float* Craw = h0;
  float* D2 = h1;

  hipMemsetAsync(bar, 0, 2048 * sizeof(unsigned), stream);

  premega_k<<<NBPRE, 256, 0, stream>>>(x, z, fc_w, fc_b, ct0_w, ct0_b, ct1_w, ct1_b,
                                       fct_w, fct_b, conv_w, conv_b,
                                       h0, h1, h2, h3, logit, sp, stored, bar);
  sag_k<<<1, 512, 0, stream>>>(D2, idx, stored, beta);
  p_k<<<512, 256, 0, stream>>>(Craw, sp, beta, Pout, Cout, rowsum);
  kl_k<<<1, 512, 0, stream>>>(rowsum, klout);
}

// Round 13
// 539.257 us; speedup vs baseline: 1.6463x; 1.6463x over previous
//
#include <hip/hip_runtime.h>
#include <hip/hip_bf16.h>
#include <math.h>

// R6 pipeline (proven 540us), sag_k control-plane scalarized:
// row indices via readfirstlane -> SGPR addresses (saddr loads), SALU bypass compares.

typedef float vf4 __attribute__((ext_vector_type(4)));

#define RFL(v) __builtin_amdgcn_readfirstlane(v)

// ---------------- FC ----------------
__global__ void fc_relu_k(const float* __restrict__ z, const float* __restrict__ w,
                          const float* __restrict__ b, float* __restrict__ out) {
  int n = blockIdx.x >> 1;
  int c0 = ((blockIdx.x & 1) << 10) + threadIdx.x * 4;
  const float* zr = z + n * 64;
  float4 acc = *(const float4*)&b[c0];
#pragma unroll
  for (int k = 0; k < 64; ++k) {
    float zk = zr[k];
    float4 wv = *(const float4*)&w[k * 2048 + c0];
    acc.x = fmaf(zk, wv.x, acc.x);
    acc.y = fmaf(zk, wv.y, acc.y);
    acc.z = fmaf(zk, wv.z, acc.z);
    acc.w = fmaf(zk, wv.w, acc.w);
  }
  acc.x = fmaxf(acc.x, 0.f); acc.y = fmaxf(acc.y, 0.f);
  acc.z = fmaxf(acc.z, 0.f); acc.w = fmaxf(acc.w, 0.f);
  *(float4*)&out[n * 2048 + c0] = acc;
}

// ---------------- ConvT (quad-gather, LDS weights — R6-proven) ----------------
#define TAPF(T, P, XV) { \
  const float4* w4_ = reinterpret_cast<const float4*>(&wt[((T) * CIN + ci) * 8]); \
  float4 wa_ = w4_[0], wb_ = w4_[1]; \
  acc[P][0] = fmaf(XV, wa_.x, acc[P][0]); \
  acc[P][1] = fmaf(XV, wa_.y, acc[P][1]); \
  acc[P][2] = fmaf(XV, wa_.z, acc[P][2]); \
  acc[P][3] = fmaf(XV, wa_.w, acc[P][3]); \
  acc[P][4] = fmaf(XV, wb_.x, acc[P][4]); \
  acc[P][5] = fmaf(XV, wb_.y, acc[P][5]); \
  acc[P][6] = fmaf(XV, wb_.z, acc[P][6]); \
  acc[P][7] = fmaf(XV, wb_.w, acc[P][7]); }

template <int CIN, int COUT, int HIN, int HOUT>
__global__ void convt_quad_k(const float* __restrict__ x, const float* __restrict__ w,
                             const float* __restrict__ bias, float* __restrict__ y) {
  constexpr bool FULL = (HOUT == 2 * HIN);
  constexpr int QP = HIN * HIN;
  __shared__ float wt[9 * CIN * 8];
  const int tid = threadIdx.x;
  const int g8 = blockIdx.y * 8;
  for (int e = tid; e < 9 * CIN * 8; e += 256) {
    int cl = e & 7;
    int rest = e >> 3;
    int ci = rest & (CIN - 1);
    int t = rest / CIN;
    wt[e] = w[((size_t)ci * COUT + g8 + cl) * 9 + t];
  }
  __syncthreads();

  int q = blockIdx.x * 256 + tid;
  int n = q / QP;
  int pq = q % QP;
  int a = pq / HIN, b = pq % HIN;
  const bool oka = (a + 1 < HIN), okb = (b + 1 < HIN);
  const float* xim = x + (size_t)n * CIN * QP + a * HIN + b;

  float acc[4][8];
#pragma unroll
  for (int p = 0; p < 4; ++p)
#pragma unroll
    for (int c = 0; c < 8; ++c) acc[p][c] = 0.f;

  for (int ci = 0; ci < CIN; ++ci) {
    const float* xc = xim + ci * QP;
    float x00 = xc[0];
    float x01 = okb ? xc[1] : 0.f;
    float x10 = oka ? xc[HIN] : 0.f;
    float x11 = (oka && okb) ? xc[HIN + 1] : 0.f;
    TAPF(4, 0, x00)
    TAPF(3, 1, x01) TAPF(5, 1, x00)
    TAPF(1, 2, x10) TAPF(7, 2, x00)
    TAPF(0, 3, x11) TAPF(2, 3, x10) TAPF(6, 3, x01) TAPF(8, 3, x00)
  }

  int oh0 = 2 * a, ow0 = 2 * b;
  bool vh = FULL || (oh0 + 1 < HOUT);
  bool vw = FULL || (ow0 + 1 < HOUT);
#pragma unroll
  for (int c = 0; c < 8; ++c) {
    float bv = bias[g8 + c];
    float o00 = fmaxf(acc[0][c] + bv, 0.f);
    float o01 = fmaxf(acc[1][c] + bv, 0.f);
    float o10 = fmaxf(acc[2][c] + bv, 0.f);
    float o11 = fmaxf(acc[3][c] + bv, 0.f);
    float* yb = y + (((size_t)n * COUT + g8 + c) * HOUT + oh0) * (size_t)HOUT + ow0;
    if (FULL) {
      *(float2*)yb = make_float2(o00, o01);
      *(float2*)(yb + HOUT) = make_float2(o10, o11);
    } else {
      yb[0] = o00;
      if (vw) yb[1] = o01;
      if (vh) yb[HOUT] = o10;
      if (vh && vw) yb[HOUT + 1] = o11;
    }
  }
}

// ---------------- final 32->1 conv ----------------
__global__ void conv_final_k(const float* __restrict__ x, const float* __restrict__ w,
                             const float* __restrict__ bias, float* __restrict__ y) {
  __shared__ float ws_[288];
  int tid = threadIdx.x;
  if (tid < 288) ws_[tid] = w[tid];
  __syncthreads();
  int gid = blockIdx.x * 256 + tid;
  int ow = gid % 28;
  int t1 = gid / 28;
  int oh = t1 % 28;
  int n = t1 / 28;
  bool h0 = oh > 0, h2 = oh < 27, w0 = ow > 0, w2 = ow < 27;
  const float* xb = x + (size_t)n * 32 * 784 + (oh - 1) * 28 + (ow - 1);
  float acc = bias[0];
  for (int ci = 0; ci < 32; ++ci) {
    const float* xc = xb + ci * 784;
    const float* wc = &ws_[ci * 9];
    if (h0 && w0) acc = fmaf(xc[0], wc[0], acc);
    if (h0)       acc = fmaf(xc[1], wc[1], acc);
    if (h0 && w2) acc = fmaf(xc[2], wc[2], acc);
    if (w0)       acc = fmaf(xc[28], wc[3], acc);
                  acc = fmaf(xc[29], wc[4], acc);
    if (w2)       acc = fmaf(xc[30], wc[5], acc);
    if (h2 && w0) acc = fmaf(xc[56], wc[6], acc);
    if (h2)       acc = fmaf(xc[57], wc[7], acc);
    if (h2 && w2) acc = fmaf(xc[58], wc[8], acc);
  }
  y[gid] = acc;
}

// ---------------- cross-lane helpers ----------------
template <int CTRL>
__device__ __forceinline__ float dpp_f(float x) {
  return __int_as_float(__builtin_amdgcn_update_dpp(0, __float_as_int(x), CTRL, 0xF, 0xF, true));
}
__device__ __forceinline__ float rdl(float v, int l) {
  return __int_as_float(__builtin_amdgcn_readlane(__float_as_int(v), l));
}
__device__ __forceinline__ float wsum64_l63(float v) {
  v += dpp_f<0xB1>(v);
  v += dpp_f<0x4E>(v);
  v += dpp_f<0x141>(v);
  v += dpp_f<0x140>(v);
  v += dpp_f<0x142>(v);
  v += dpp_f<0x143>(v);
  return rdl(v, 63);
}
__device__ __forceinline__ float wmax64_l63(float v) {
  v = fmaxf(v, dpp_f<0xB1>(v));
  v = fmaxf(v, dpp_f<0x4E>(v));
  v = fmaxf(v, dpp_f<0x141>(v));
  v = fmaxf(v, dpp_f<0x140>(v));
  v = fmaxf(v, dpp_f<0x142>(v));
  v = fmaxf(v, dpp_f<0x143>(v));
  return rdl(v, 63);
}

// ---------------- cost GEMM 32x64 + fused softplus row sums ----------------
__global__ void cost_k(const float* __restrict__ X, const float* __restrict__ L,
                       float* __restrict__ Craw, float* __restrict__ sp) {
  __shared__ float Xs[16][36];
  __shared__ float Ls[16][68];
  int tid = threadIdx.x;
  int i0 = blockIdx.y * 32, j0 = blockIdx.x * 64;
  int lrow = tid >> 2;
  int lq = tid & 3;
  int xrow = tid & 31;
  int xq = (tid >> 5) & 3;
  bool doX = tid < 128;
  bool doSP = (blockIdx.y == 0);
  int tx = tid & 15, ty = tid >> 4;
  float acc[2][4] = {};
  float spacc = 0.f;
  for (int k0 = 0; k0 < 784; k0 += 16) {
    float4 lv = *(const float4*)&L[(size_t)(j0 + lrow) * 784 + k0 + lq * 4];
    float4 xv = {0.f, 0.f, 0.f, 0.f};
    if (doX) xv = *(const float4*)&X[(size_t)(i0 + xrow) * 784 + k0 + xq * 4];
    __syncthreads();
    Ls[lq * 4 + 0][lrow] = lv.x; Ls[lq * 4 + 1][lrow] = lv.y;
    Ls[lq * 4 + 2][lrow] = lv.z; Ls[lq * 4 + 3][lrow] = lv.w;
    if (doX) {
      Xs[xq * 4 + 0][xrow] = xv.x; Xs[xq * 4 + 1][xrow] = xv.y;
      Xs[xq * 4 + 2][xrow] = xv.z; Xs[xq * 4 + 3][xrow] = xv.w;
    }
    if (doSP) {
      spacc += fmaxf(lv.x, 0.f) + log1pf(__expf(-fabsf(lv.x)));
      spacc += fmaxf(lv.y, 0.f) + log1pf(__expf(-fabsf(lv.y)));
      spacc += fmaxf(lv.z, 0.f) + log1pf(__expf(-fabsf(lv.z)));
      spacc += fmaxf(lv.w, 0.f) + log1pf(__expf(-fabsf(lv.w)));
    }
    __syncthreads();
#pragma unroll
    for (int k = 0; k < 16; ++k) {
      float2 a = *(const float2*)&Xs[k][ty * 2];
      float4 bq = *(const float4*)&Ls[k][tx * 4];
      acc[0][0] = fmaf(a.x, bq.x, acc[0][0]); acc[0][1] = fmaf(a.x, bq.y, acc[0][1]);
      acc[0][2] = fmaf(a.x, bq.z, acc[0][2]); acc[0][3] = fmaf(a.x, bq.w, acc[0][3]);
      acc[1][0] = fmaf(a.y, bq.x, acc[1][0]); acc[1][1] = fmaf(a.y, bq.y, acc[1][1]);
      acc[1][2] = fmaf(a.y, bq.z, acc[1][2]); acc[1][3] = fmaf(a.y, bq.w, acc[1][3]);
    }
  }
#pragma unroll
  for (int r = 0; r < 2; ++r) {
    float4 o = make_float4(acc[r][0], acc[r][1], acc[r][2], acc[r][3]);
    *(float4*)&Craw[(size_t)(i0 + ty * 2 + r) * 512 + j0 + tx * 4] = o;
  }
  if (doSP) {
    float q = spacc;
    q += dpp_f<0xB1>(q);
    q += dpp_f<0x4E>(q);
    if (lq == 0) sp[j0 + lrow] = q;
  }
}

// ---------------- prep: rowmax + shifted/log2e-scaled cost ----------------
__global__ void prep_k(const float* __restrict__ craw, const float* __restrict__ sp,
                       float* __restrict__ D2) {
  __shared__ float red[256];
  int i = blockIdx.x, tid = threadIdx.x;
  float c0 = craw[(size_t)i * 512 + tid];
  float c1 = craw[(size_t)i * 512 + tid + 256];
  float v0 = c0 - sp[tid];
  float v1 = c1 - sp[tid + 256];
  red[tid] = fmaxf(v0, v1);
  __syncthreads();
  for (int st = 128; st > 0; st >>= 1) {
    if (tid < st) red[tid] = fmaxf(red[tid], red[tid + st]);
    __syncthreads();
  }
  float m = red[0];
  const float L2E = 1.4426950408889634f;
  D2[(size_t)i * 512 + tid] = (m - v0) * L2E;
  D2[(size_t)i * 512 + tid + 256] = (m - v1) * L2E;
}

// ---------------- SAG scan (single wave, scalar control plane) ----------------
// Row indices are SGPRs (readfirstlane) -> saddr loads (voffset = jb*4 fixed),
// SALU bypass compares + s_cbranch around the rare cndmask body.
#define SLD0(ROW) { const float* cp_ = D2 + ((size_t)(unsigned)(ROW) << 9) + jb; \
  s0dA = *(const vf4*)cp_; s0dB = *(const vf4*)(cp_ + 4); \
  const float* tp_ = stored + ((size_t)(unsigned)(ROW) << 9) + jb; \
  s0sA = *(const vf4*)tp_; s0sB = *(const vf4*)(tp_ + 4); }
#define SLD1(ROW) { const float* cp_ = D2 + ((size_t)(unsigned)(ROW) << 9) + jb; \
  s1dA = *(const vf4*)cp_; s1dB = *(const vf4*)(cp_ + 4); \
  const float* tp_ = stored + ((size_t)(unsigned)(ROW) << 9) + jb; \
  s1sA = *(const vf4*)tp_; s1sB = *(const vf4*)(tp_ + 4); }

#define STEP(RR, PFR, DA, DB, SA, SB, LDM, \
             R1,A1,B1, R2,A2,B2, R3,A3,B3, R4,A4,B4, R5,A5,B5, R6,A6,B6, \
             GA, GB) \
{ \
  vf4 d0_ = DA, d1_ = DB, t0_ = SA, t1_ = SB; \
  LDM(PFR); \
  const int r_ = (RR); \
  if (__builtin_expect((r_==(R1)) | (r_==(R2)) | (r_==(R3)) | \
                       (r_==(R4)) | (r_==(R5)) | (r_==(R6)), 0)) { \
    if (r_==(R6)) { t0_ = A6; t1_ = B6; } \
    if (r_==(R5)) { t0_ = A5; t1_ = B5; } \
    if (r_==(R4)) { t0_ = A4; t1_ = B4; } \
    if (r_==(R3)) { t0_ = A3; t1_ = B3; } \
    if (r_==(R2)) { t0_ = A2; t1_ = B2; } \
    if (r_==(R1)) { t0_ = A1; t1_ = B1; } \
  } \
  vf4 u0_ = ssumL - t0_; \
  vf4 u1_ = ssumH - t1_; \
  vf4 a0_ = betaL - d0_; \
  vf4 a1_ = betaH - d1_; \
  vf4 e0_, e1_; \
  e0_.x = __builtin_amdgcn_exp2f(a0_.x); e0_.y = __builtin_amdgcn_exp2f(a0_.y); \
  e0_.z = __builtin_amdgcn_exp2f(a0_.z); e0_.w = __builtin_amdgcn_exp2f(a0_.w); \
  e1_.x = __builtin_amdgcn_exp2f(a1_.x); e1_.y = __builtin_amdgcn_exp2f(a1_.y); \
  e1_.z = __builtin_amdgcn_exp2f(a1_.z); e1_.w = __builtin_amdgcn_exp2f(a1_.w); \
  vf4 es_ = e0_ + e1_; \
  float S_ = wsum64_l63((es_.x + es_.z) + (es_.y + es_.w)); \
  S_ = fmaxf(S_, 1e-35f); \
  float kk_ = C2NL * __builtin_amdgcn_rcpf(S_); \
  vf4 g0_ = e0_ * kk_ + c1l4; \
  vf4 g1_ = e1_ * kk_ + c1l4; \
  ssumL = u0_ + g0_; ssumH = u1_ + g1_; \
  betaL += ssumL; betaH += ssumH; \
  float* wp_ = stored + ((size_t)(unsigned)r_ << 9) + jb; \
  *(vf4*)wp_ = g0_; *(vf4*)(wp_ + 4) = g1_; \
  GA = g0_; GB = g1_; \
}

__global__ void __launch_bounds__(512, 1) sag_k(const float* __restrict__ D2,
                                                const int* __restrict__ idx,
                                                float* __restrict__ stored,
                                                float* __restrict__ beta_out) {
  const int tid = threadIdx.x;
  if (tid >= 64) {
    // waves 1-7: warm D2 + stored into this XCD's L2 while wave 0 scans
    const vf4* c4 = (const vf4*)D2;
    const vf4* s4 = (const vf4*)stored;
    vf4 acc = {0.f, 0.f, 0.f, 0.f};
    for (int p = tid - 64; p < 65536; p += 448) { acc += c4[p]; acc += s4[p]; }
    float accs = acc.x + acc.y + acc.z + acc.w;
    asm volatile("" :: "v"(accs));
    return;
  }

  const int jb = tid * 8;
  const float C2NL = -0.0028177637f;                 // -(1/512)*log2e
  const vf4 c1l4 = {5.503574e-06f, 5.503574e-06f, 5.503574e-06f, 5.503574e-06f};

  vf4 z4 = {0.f, 0.f, 0.f, 0.f};
  vf4 betaL = z4, betaH = z4, ssumL = z4, ssumH = z4;
  vf4 h1A = z4, h1B = z4, h2A = z4, h2B = z4, h3A = z4, h3B = z4;
  vf4 h4A = z4, h4B = z4, h5A = z4, h5B = z4, h6A = z4, h6B = z4;
  int hr1 = -1, hr2 = -1, hr3 = -1, hr4 = -1, hr5 = -1, hr6 = -1;
  float vsh = 0.f;

  // scalar row indices (SGPR)
  int i0 = RFL(idx[0]), i1 = RFL(idx[1]), i2 = RFL(idx[2]), i3 = RFL(idx[3]);
  int i4 = RFL(idx[4]), i5 = RFL(idx[5]), i6 = RFL(idx[6]), i7 = RFL(idx[7]);

  vf4 s0dA, s0dB, s0sA, s0sB, s1dA, s1dB, s1sA, s1sB;
  SLD0(i0);
  SLD1(i1);

  vf4 g0a, g0b, g1a, g1b, g2a, g2b, g3a, g3b;
  vf4 g4a, g4b, g5a, g5b, g6a, g6b, g7a, g7b;

  for (int t = 0; t < 1000; t += 8) {
    int tb = (t + 8 < 1000) ? (t + 8) : 992;
    int n0 = RFL(idx[tb + 0]), n1 = RFL(idx[tb + 1]);
    int n2 = RFL(idx[tb + 2]), n3 = RFL(idx[tb + 3]);
    int n4 = RFL(idx[tb + 4]), n5 = RFL(idx[tb + 5]);
    int n6 = RFL(idx[tb + 6]), n7 = RFL(idx[tb + 7]);

    STEP(i0, i2, s0dA, s0dB, s0sA, s0sB, SLD0,
         hr1,h1A,h1B, hr2,h2A,h2B, hr3,h3A,h3B, hr4,h4A,h4B, hr5,h5A,h5B, hr6,h6A,h6B,
         g0a, g0b)
    STEP(i1, i3, s1dA, s1dB, s1sA, s1sB, SLD1,
         i0,g0a,g0b, hr1,h1A,h1B, hr2,h2A,h2B, hr3,h3A,h3B, hr4,h4A,h4B, hr5,h5A,h5B,
         g1a, g1b)
    STEP(i2, i4, s0dA, s0dB, s0sA, s0sB, SLD0,
         i1,g1a,g1b, i0,g0a,g0b, hr1,h1A,h1B, hr2,h2A,h2B, hr3,h3A,h3B, hr4,h4A,h4B,
         g2a, g2b)
    STEP(i3, i5, s1dA, s1dB, s1sA, s1sB, SLD1,
         i2,g2a,g2b, i1,g1a,g1b, i0,g0a,g0b, hr1,h1A,h1B, hr2,h2A,h2B, hr3,h3A,h3B,
         g3a, g3b)
    STEP(i4, i6, s0dA, s0dB, s0sA, s0sB, SLD0,
         i3,g3a,g3b, i2,g2a,g2b, i1,g1a,g1b, i0,g0a,g0b, hr1,h1A,h1B, hr2,h2A,h2B,
         g4a, g4b)
    STEP(i5, i7, s1dA, s1dB, s1sA, s1sB, SLD1,
         i4,g4a,g4b, i3,g3a,g3b, i2,g2a,g2b, i1,g1a,g1b, i0,g0a,g0b, hr1,h1A,h1B,
         g5a, g5b)
    STEP(i6, n0, s0dA, s0dB, s0sA, s0sB, SLD0,
         i5,g5a,g5b, i4,g4a,g4b, i3,g3a,g3b, i2,g2a,g2b, i1,g1a,g1b, i0,g0a,g0b,
         g6a, g6b)
    STEP(i7, n1, s1dA, s1dB, s1sA, s1sB, SLD1,
         i6,g6a,g6b, i5,g5a,g5b, i4,g4a,g4b, i3,g3a,g3b, i2,g2a,g2b, i1,g1a,g1b,
         g7a, g7b)

    // recenter beta~ once per 8 steps (uniform shift -> exact)
    {
      vf4 qm;
      qm.x = fmaxf(betaL.x, betaH.x); qm.y = fmaxf(betaL.y, betaH.y);
      qm.z = fmaxf(betaL.z, betaH.z); qm.w = fmaxf(betaL.w, betaH.w);
      float lm = fmaxf(fmaxf(qm.x, qm.y), fmaxf(qm.z, qm.w));
      float dm = wmax64_l63(lm);
      betaL = betaL - dm; betaH = betaH - dm;
      vsh += dm;
    }

    hr1 = i7; h1A = g7a; h1B = g7b;
    hr2 = i6; h2A = g6a; h2B = g6b;
    hr3 = i5; h3A = g5a; h3B = g5b;
    hr4 = i4; h4A = g4a; h4B = g4b;
    hr5 = i3; h5A = g3a; h5B = g3b;
    hr6 = i2; h6A = g2a; h6B = g2b;
    i0 = n0; i1 = n1; i2 = n2; i3 = n3;
    i4 = n4; i5 = n5; i6 = n6; i7 = n7;
  }

  const float LN2 = 0.6931471805599453f;
  vf4 oL = (betaL + vsh) * LN2;
  vf4 oH = (betaH + vsh) * LN2;
  *(vf4*)(beta_out + jb) = oL;
  *(vf4*)(beta_out + jb + 4) = oH;
}

// ---------------- plan recovery + C output + entropy rows ----------------
__global__ void p_k(const float* __restrict__ craw, const float* __restrict__ sp,
                    const float* __restrict__ beta, float* __restrict__ P,
                    float* __restrict__ Cout, float* __restrict__ rowsum) {
  __shared__ float red[256];
  int i = blockIdx.x, tid = threadIdx.x;
  float c0 = craw[(size_t)i * 512 + tid];
  float c1 = craw[(size_t)i * 512 + tid + 256];
  float sp0 = sp[tid], sp1 = sp[tid + 256];
  float u0 = (beta[tid] - sp0) + c0;
  float u1 = (beta[tid + 256] - sp1) + c1;
  Cout[(size_t)i * 512 + tid] = sp0 - c0;
  Cout[(size_t)i * 512 + tid + 256] = sp1 - c1;
  float m = fmaxf(u0, u1);
  red[tid] = m;
  __syncthreads();
  for (int st = 128; st > 0; st >>= 1) {
    if (tid < st) red[tid] = fmaxf(red[tid], red[tid + st]);
    __syncthreads();
  }
  m = red[0];
  __syncthreads();
  float e0 = __expf(u0 - m), e1 = __expf(u1 - m);
  red[tid] = e0 + e1;
  __syncthreads();
  for (int st = 128; st > 0; st >>= 1) {
    if (tid < st) red[tid] += red[tid + st];
    __syncthreads();
  }
  float lse = m + logf(red[0]);
  __syncthreads();
  const float log512 = 6.238324625039508f;
  float p0 = __expf(u0 - lse) * (1.0f / 512.0f);
  float p1 = __expf(u1 - lse) * (1.0f / 512.0f);
  P[(size_t)i * 512 + tid] = p0;
  P[(size_t)i * 512 + tid + 256] = p1;
  float pl = p0 * (u0 - lse - log512) + p1 * (u1 - lse - log512);
  red[tid] = pl;
  __syncthreads();
  for (int st = 128; st > 0; st >>= 1) {
    if (tid < st) red[tid] += red[tid + st];
    __syncthreads();
  }
  if (tid == 0) rowsum[i] = red[0];
}

__global__ void kl_k(const float* __restrict__ rowsum, float* __restrict__ out_kl) {
  __shared__ float red[512];
  int tid = threadIdx.x;
  red[tid] = rowsum[tid];
  __syncthreads();
  for (int st = 256; st > 0; st >>= 1) {
    if (tid < st) red[tid] += red[tid + st];
    __syncthreads();
  }
  if (tid == 0) out_kl[0] = red[0] + 2.0f * 6.238324625039508f;
}

extern "C" void kernel_launch(void* const* d_in, const int* in_sizes, int n_in,
                              void* d_out, int out_size, void* d_ws, size_t ws_size,
                              hipStream_t stream) {
  const float* x = (const float*)d_in[0];
  const float* z = (const float*)d_in[1];
  const float* fc_w = (const float*)d_in[2];
  const float* fc_b = (const float*)d_in[3];
  const float* ct0_w = (const float*)d_in[4];
  const float* ct0_b = (const float*)d_in[5];
  const float* ct1_w = (const float*)d_in[6];
  const float* ct1_b = (const float*)d_in[7];
  const float* fct_w = (const float*)d_in[8];
  const float* fct_b = (const float*)d_in[9];
  const float* conv_w = (const float*)d_in[10];
  const float* conv_b = (const float*)d_in[11];
  const int* idx = (const int*)d_in[12];

  float* out = (float*)d_out;
  float* Pout = out;               // 512*512
  float* Cout = out + 262144;      // 512*512
  float* klout = out + 524288;     // 1

  float* ws = (float*)d_ws;
  float* h0 = ws;                       // 512*2048   (-> Craw after ct0)
  float* h1 = h0 + 1048576;             // 512*64*49  (-> D2 after ct1)
  float* h2 = h1 + 1605632;             // 512*32*196
  float* h3 = h2 + 3211264;             // 512*32*784
  float* logit = h3 + 12845056;         // 512*784
  float* sp = logit + 401408;           // 512
  float* beta = sp + 512;               // 512
  float* stored = beta + 512;           // 512*512
  float* rowsum = stored + 262144;      // 512
  float* Craw = h0;
  float* D2 = h1;

  hipMemsetAsync(stored, 0, 262144 * sizeof(float), stream);

  fc_relu_k<<<1024, 256, 0, stream>>>(z, fc_w, fc_b, h0);
  convt_quad_k<128, 64, 4, 7><<<dim3(32, 8), 256, 0, stream>>>(h0, ct0_w, ct0_b, h1);
  convt_quad_k<64, 32, 7, 14><<<dim3(98, 4), 256, 0, stream>>>(h1, ct1_w, ct1_b, h2);
  convt_quad_k<32, 32, 14, 28><<<dim3(392, 4), 256, 0, stream>>>(h2, fct_w, fct_b, h3);
  conv_final_k<<<1568, 256, 0, stream>>>(h3, conv_w, conv_b, logit);
  cost_k<<<dim3(8, 16), 256, 0, stream>>>(x, logit, Craw, sp);
  prep_k<<<512, 256, 0, stream>>>(Craw, sp, D2);
  sag_k<<<1, 512, 0, stream>>>(D2, idx, stored, beta);
  p_k<<<512, 256, 0, stream>>>(Craw, sp, beta, Pout, Cout, rowsum);
  kl_k<<<1, 512, 0, stream>>>(rowsum, klout);
}

// Round 14
// 530.267 us; speedup vs baseline: 1.6742x; 1.0170x over previous
//
#include <hip/hip_runtime.h>
#include <hip/hip_bf16.h>
#include <math.h>

// R13 pipeline (539us) with image-paired convT/conv_final:
// each thread computes 2 images (n, n+256) -> every LDS weight read amortized
// over 2x the fma work (convT was LDS-pipe-bound at 18 b128 : 144 VALU cyc/ci).
// GW=4 co-groups keep grids >= 1 block/CU. Per-output fma order unchanged.

typedef float vf4 __attribute__((ext_vector_type(4)));

#define RFL(v) __builtin_amdgcn_readfirstlane(v)

// ---------------- FC ----------------
__global__ void fc_relu_k(const float* __restrict__ z, const float* __restrict__ w,
                          const float* __restrict__ b, float* __restrict__ out) {
  int n = blockIdx.x >> 1;
  int c0 = ((blockIdx.x & 1) << 10) + threadIdx.x * 4;
  const float* zr = z + n * 64;
  float4 acc = *(const float4*)&b[c0];
#pragma unroll
  for (int k = 0; k < 64; ++k) {
    float zk = zr[k];
    float4 wv = *(const float4*)&w[k * 2048 + c0];
    acc.x = fmaf(zk, wv.x, acc.x);
    acc.y = fmaf(zk, wv.y, acc.y);
    acc.z = fmaf(zk, wv.z, acc.z);
    acc.w = fmaf(zk, wv.w, acc.w);
  }
  acc.x = fmaxf(acc.x, 0.f); acc.y = fmaxf(acc.y, 0.f);
  acc.z = fmaxf(acc.z, 0.f); acc.w = fmaxf(acc.w, 0.f);
  *(float4*)&out[n * 2048 + c0] = acc;
}

// ---------------- ConvT (quad-gather, image-paired, GW=4) ----------------
#define TAPF4(T, P, XV0, XV1) { \
  float4 wv_ = *reinterpret_cast<const float4*>(&wt[((T) * CIN + ci) * 4]); \
  acc0[P][0] = fmaf(XV0, wv_.x, acc0[P][0]); \
  acc0[P][1] = fmaf(XV0, wv_.y, acc0[P][1]); \
  acc0[P][2] = fmaf(XV0, wv_.z, acc0[P][2]); \
  acc0[P][3] = fmaf(XV0, wv_.w, acc0[P][3]); \
  acc1[P][0] = fmaf(XV1, wv_.x, acc1[P][0]); \
  acc1[P][1] = fmaf(XV1, wv_.y, acc1[P][1]); \
  acc1[P][2] = fmaf(XV1, wv_.z, acc1[P][2]); \
  acc1[P][3] = fmaf(XV1, wv_.w, acc1[P][3]); }

template <int CIN, int COUT, int HIN, int HOUT>
__global__ void convt_pair_k(const float* __restrict__ x, const float* __restrict__ w,
                             const float* __restrict__ bias, float* __restrict__ y) {
  constexpr bool FULL = (HOUT == 2 * HIN);
  constexpr int QP = HIN * HIN;
  __shared__ float wt[9 * CIN * 4];
  const int tid = threadIdx.x;
  const int g4 = blockIdx.y * 4;
  for (int e = tid; e < 9 * CIN * 4; e += 256) {
    int cl = e & 3;
    int rest = e >> 2;
    int ci = rest & (CIN - 1);
    int t = rest / CIN;
    wt[e] = w[((size_t)ci * COUT + g4 + cl) * 9 + t];
  }
  __syncthreads();

  int q = blockIdx.x * 256 + tid;       // 256 image-pairs x QP positions
  int np = q / QP;                      // 0..255 -> images np, np+256
  int pq = q % QP;
  int a = pq / HIN, b = pq % HIN;
  const bool oka = (a + 1 < HIN), okb = (b + 1 < HIN);
  const float* xim0 = x + (size_t)np * CIN * QP + a * HIN + b;
  const float* xim1 = x + (size_t)(np + 256) * CIN * QP + a * HIN + b;

  float acc0[4][4], acc1[4][4];
#pragma unroll
  for (int p = 0; p < 4; ++p)
#pragma unroll
    for (int c = 0; c < 4; ++c) { acc0[p][c] = 0.f; acc1[p][c] = 0.f; }

  for (int ci = 0; ci < CIN; ++ci) {
    const float* xc0 = xim0 + ci * QP;
    const float* xc1 = xim1 + ci * QP;
    float p00 = xc0[0];
    float p01 = okb ? xc0[1] : 0.f;
    float p10 = oka ? xc0[HIN] : 0.f;
    float p11 = (oka && okb) ? xc0[HIN + 1] : 0.f;
    float q00 = xc1[0];
    float q01 = okb ? xc1[1] : 0.f;
    float q10 = oka ? xc1[HIN] : 0.f;
    float q11 = (oka && okb) ? xc1[HIN + 1] : 0.f;
    TAPF4(4, 0, p00, q00)
    TAPF4(3, 1, p01, q01) TAPF4(5, 1, p00, q00)
    TAPF4(1, 2, p10, q10) TAPF4(7, 2, p00, q00)
    TAPF4(0, 3, p11, q11) TAPF4(2, 3, p10, q10) TAPF4(6, 3, p01, q01) TAPF4(8, 3, p00, q00)
  }

  int oh0 = 2 * a, ow0 = 2 * b;
  bool vh = FULL || (oh0 + 1 < HOUT);
  bool vw = FULL || (ow0 + 1 < HOUT);
#pragma unroll
  for (int c = 0; c < 4; ++c) {
    float bv = bias[g4 + c];
    float a00 = fmaxf(acc0[0][c] + bv, 0.f);
    float a01 = fmaxf(acc0[1][c] + bv, 0.f);
    float a10 = fmaxf(acc0[2][c] + bv, 0.f);
    float a11 = fmaxf(acc0[3][c] + bv, 0.f);
    float b00 = fmaxf(acc1[0][c] + bv, 0.f);
    float b01 = fmaxf(acc1[1][c] + bv, 0.f);
    float b10 = fmaxf(acc1[2][c] + bv, 0.f);
    float b11 = fmaxf(acc1[3][c] + bv, 0.f);
    float* yb0 = y + (((size_t)np * COUT + g4 + c) * HOUT + oh0) * (size_t)HOUT + ow0;
    float* yb1 = y + (((size_t)(np + 256) * COUT + g4 + c) * HOUT + oh0) * (size_t)HOUT + ow0;
    if (FULL) {
      *(float2*)yb0 = make_float2(a00, a01);
      *(float2*)(yb0 + HOUT) = make_float2(a10, a11);
      *(float2*)yb1 = make_float2(b00, b01);
      *(float2*)(yb1 + HOUT) = make_float2(b10, b11);
    } else {
      yb0[0] = a00;
      yb1[0] = b00;
      if (vw) { yb0[1] = a01; yb1[1] = b01; }
      if (vh) { yb0[HOUT] = a10; yb1[HOUT] = b10; }
      if (vh && vw) { yb0[HOUT + 1] = a11; yb1[HOUT + 1] = b11; }
    }
  }
}

// ---------------- final 32->1 conv (image-paired) ----------------
__global__ void conv_final_pair_k(const float* __restrict__ x, const float* __restrict__ w,
                                  const float* __restrict__ bias, float* __restrict__ y) {
  __shared__ float ws_[288];
  int tid = threadIdx.x;
  if (tid < 288) ws_[tid] = w[tid];
  __syncthreads();
  int gid = blockIdx.x * 256 + tid;     // 256 pairs x 784 px = 200704
  int px = gid % 784;
  int np = gid / 784;
  int ow = px % 28;
  int oh = px / 28;
  bool h0 = oh > 0, h2 = oh < 27, w0 = ow > 0, w2 = ow < 27;
  const float* xb0 = x + (size_t)np * 32 * 784 + (oh - 1) * 28 + (ow - 1);
  const float* xb1 = x + (size_t)(np + 256) * 32 * 784 + (oh - 1) * 28 + (ow - 1);
  float acc0 = bias[0], acc1 = bias[0];
  for (int ci = 0; ci < 32; ++ci) {
    const float* xc0 = xb0 + ci * 784;
    const float* xc1 = xb1 + ci * 784;
    const float* wc = &ws_[ci * 9];
    if (h0 && w0) { acc0 = fmaf(xc0[0], wc[0], acc0); acc1 = fmaf(xc1[0], wc[0], acc1); }
    if (h0)       { acc0 = fmaf(xc0[1], wc[1], acc0); acc1 = fmaf(xc1[1], wc[1], acc1); }
    if (h0 && w2) { acc0 = fmaf(xc0[2], wc[2], acc0); acc1 = fmaf(xc1[2], wc[2], acc1); }
    if (w0)       { acc0 = fmaf(xc0[28], wc[3], acc0); acc1 = fmaf(xc1[28], wc[3], acc1); }
                    acc0 = fmaf(xc0[29], wc[4], acc0); acc1 = fmaf(xc1[29], wc[4], acc1);
    if (w2)       { acc0 = fmaf(xc0[30], wc[5], acc0); acc1 = fmaf(xc1[30], wc[5], acc1); }
    if (h2 && w0) { acc0 = fmaf(xc0[56], wc[6], acc0); acc1 = fmaf(xc1[56], wc[6], acc1); }
    if (h2)       { acc0 = fmaf(xc0[57], wc[7], acc0); acc1 = fmaf(xc1[57], wc[7], acc1); }
    if (h2 && w2) { acc0 = fmaf(xc0[58], wc[8], acc0); acc1 = fmaf(xc1[58], wc[8], acc1); }
  }
  y[(size_t)np * 784 + px] = acc0;
  y[(size_t)(np + 256) * 784 + px] = acc1;
}

// ---------------- cross-lane helpers ----------------
template <int CTRL>
__device__ __forceinline__ float dpp_f(float x) {
  return __int_as_float(__builtin_amdgcn_update_dpp(0, __float_as_int(x), CTRL, 0xF, 0xF, true));
}
__device__ __forceinline__ float rdl(float v, int l) {
  return __int_as_float(__builtin_amdgcn_readlane(__float_as_int(v), l));
}
__device__ __forceinline__ float wsum64_l63(float v) {
  v += dpp_f<0xB1>(v);
  v += dpp_f<0x4E>(v);
  v += dpp_f<0x141>(v);
  v += dpp_f<0x140>(v);
  v += dpp_f<0x142>(v);
  v += dpp_f<0x143>(v);
  return rdl(v, 63);
}
__device__ __forceinline__ float wmax64_l63(float v) {
  v = fmaxf(v, dpp_f<0xB1>(v));
  v = fmaxf(v, dpp_f<0x4E>(v));
  v = fmaxf(v, dpp_f<0x141>(v));
  v = fmaxf(v, dpp_f<0x140>(v));
  v = fmaxf(v, dpp_f<0x142>(v));
  v = fmaxf(v, dpp_f<0x143>(v));
  return rdl(v, 63);
}

// ---------------- cost GEMM 32x64 + fused softplus row sums ----------------
__global__ void cost_k(const float* __restrict__ X, const float* __restrict__ L,
                       float* __restrict__ Craw, float* __restrict__ sp) {
  __shared__ float Xs[16][36];
  __shared__ float Ls[16][68];
  int tid = threadIdx.x;
  int i0 = blockIdx.y * 32, j0 = blockIdx.x * 64;
  int lrow = tid >> 2;
  int lq = tid & 3;
  int xrow = tid & 31;
  int xq = (tid >> 5) & 3;
  bool doX = tid < 128;
  bool doSP = (blockIdx.y == 0);
  int tx = tid & 15, ty = tid >> 4;
  float acc[2][4] = {};
  float spacc = 0.f;
  for (int k0 = 0; k0 < 784; k0 += 16) {
    float4 lv = *(const float4*)&L[(size_t)(j0 + lrow) * 784 + k0 + lq * 4];
    float4 xv = {0.f, 0.f, 0.f, 0.f};
    if (doX) xv = *(const float4*)&X[(size_t)(i0 + xrow) * 784 + k0 + xq * 4];
    __syncthreads();
    Ls[lq * 4 + 0][lrow] = lv.x; Ls[lq * 4 + 1][lrow] = lv.y;
    Ls[lq * 4 + 2][lrow] = lv.z; Ls[lq * 4 + 3][lrow] = lv.w;
    if (doX) {
      Xs[xq * 4 + 0][xrow] = xv.x; Xs[xq * 4 + 1][xrow] = xv.y;
      Xs[xq * 4 + 2][xrow] = xv.z; Xs[xq * 4 + 3][xrow] = xv.w;
    }
    if (doSP) {
      spacc += fmaxf(lv.x, 0.f) + log1pf(__expf(-fabsf(lv.x)));
      spacc += fmaxf(lv.y, 0.f) + log1pf(__expf(-fabsf(lv.y)));
      spacc += fmaxf(lv.z, 0.f) + log1pf(__expf(-fabsf(lv.z)));
      spacc += fmaxf(lv.w, 0.f) + log1pf(__expf(-fabsf(lv.w)));
    }
    __syncthreads();
#pragma unroll
    for (int k = 0; k < 16; ++k) {
      float2 a = *(const float2*)&Xs[k][ty * 2];
      float4 bq = *(const float4*)&Ls[k][tx * 4];
      acc[0][0] = fmaf(a.x, bq.x, acc[0][0]); acc[0][1] = fmaf(a.x, bq.y, acc[0][1]);
      acc[0][2] = fmaf(a.x, bq.z, acc[0][2]); acc[0][3] = fmaf(a.x, bq.w, acc[0][3]);
      acc[1][0] = fmaf(a.y, bq.x, acc[1][0]); acc[1][1] = fmaf(a.y, bq.y, acc[1][1]);
      acc[1][2] = fmaf(a.y, bq.z, acc[1][2]); acc[1][3] = fmaf(a.y, bq.w, acc[1][3]);
    }
  }
#pragma unroll
  for (int r = 0; r < 2; ++r) {
    float4 o = make_float4(acc[r][0], acc[r][1], acc[r][2], acc[r][3]);
    *(float4*)&Craw[(size_t)(i0 + ty * 2 + r) * 512 + j0 + tx * 4] = o;
  }
  if (doSP) {
    float q = spacc;
    q += dpp_f<0xB1>(q);
    q += dpp_f<0x4E>(q);
    if (lq == 0) sp[j0 + lrow] = q;
  }
}

// ---------------- prep: rowmax + shifted/log2e-scaled cost ----------------
__global__ void prep_k(const float* __restrict__ craw, const float* __restrict__ sp,
                       float* __restrict__ D2) {
  __shared__ float red[256];
  int i = blockIdx.x, tid = threadIdx.x;
  float c0 = craw[(size_t)i * 512 + tid];
  float c1 = craw[(size_t)i * 512 + tid + 256];
  float v0 = c0 - sp[tid];
  float v1 = c1 - sp[tid + 256];
  red[tid] = fmaxf(v0, v1);
  __syncthreads();
  for (int st = 128; st > 0; st >>= 1) {
    if (tid < st) red[tid] = fmaxf(red[tid], red[tid + st]);
    __syncthreads();
  }
  float m = red[0];
  const float L2E = 1.4426950408889634f;
  D2[(size_t)i * 512 + tid] = (m - v0) * L2E;
  D2[(size_t)i * 512 + tid + 256] = (m - v1) * L2E;
}

// ---------------- SAG scan (single wave; R13-proven) ----------------
#define SLD0(ROW) { const float* cp_ = D2 + ((size_t)(unsigned)(ROW) << 9) + jb; \
  s0dA = *(const vf4*)cp_; s0dB = *(const vf4*)(cp_ + 4); \
  const float* tp_ = stored + ((size_t)(unsigned)(ROW) << 9) + jb; \
  s0sA = *(const vf4*)tp_; s0sB = *(const vf4*)(tp_ + 4); }
#define SLD1(ROW) { const float* cp_ = D2 + ((size_t)(unsigned)(ROW) << 9) + jb; \
  s1dA = *(const vf4*)cp_; s1dB = *(const vf4*)(cp_ + 4); \
  const float* tp_ = stored + ((size_t)(unsigned)(ROW) << 9) + jb; \
  s1sA = *(const vf4*)tp_; s1sB = *(const vf4*)(tp_ + 4); }

#define STEP(RR, PFR, DA, DB, SA, SB, LDM, \
             R1,A1,B1, R2,A2,B2, R3,A3,B3, R4,A4,B4, R5,A5,B5, R6,A6,B6, \
             GA, GB) \
{ \
  vf4 d0_ = DA, d1_ = DB, t0_ = SA, t1_ = SB; \
  LDM(PFR); \
  const int r_ = (RR); \
  if (__builtin_expect((r_==(R1)) | (r_==(R2)) | (r_==(R3)) | \
                       (r_==(R4)) | (r_==(R5)) | (r_==(R6)), 0)) { \
    if (r_==(R6)) { t0_ = A6; t1_ = B6; } \
    if (r_==(R5)) { t0_ = A5; t1_ = B5; } \
    if (r_==(R4)) { t0_ = A4; t1_ = B4; } \
    if (r_==(R3)) { t0_ = A3; t1_ = B3; } \
    if (r_==(R2)) { t0_ = A2; t1_ = B2; } \
    if (r_==(R1)) { t0_ = A1; t1_ = B1; } \
  } \
  vf4 u0_ = ssumL - t0_; \
  vf4 u1_ = ssumH - t1_; \
  vf4 a0_ = betaL - d0_; \
  vf4 a1_ = betaH - d1_; \
  vf4 e0_, e1_; \
  e0_.x = __builtin_amdgcn_exp2f(a0_.x); e0_.y = __builtin_amdgcn_exp2f(a0_.y); \
  e0_.z = __builtin_amdgcn_exp2f(a0_.z); e0_.w = __builtin_amdgcn_exp2f(a0_.w); \
  e1_.x = __builtin_amdgcn_exp2f(a1_.x); e1_.y = __builtin_amdgcn_exp2f(a1_.y); \
  e1_.z = __builtin_amdgcn_exp2f(a1_.z); e1_.w = __builtin_amdgcn_exp2f(a1_.w); \
  vf4 es_ = e0_ + e1_; \
  float S_ = wsum64_l63((es_.x + es_.z) + (es_.y + es_.w)); \
  S_ = fmaxf(S_, 1e-35f); \
  float kk_ = C2NL * __builtin_amdgcn_rcpf(S_); \
  vf4 g0_ = e0_ * kk_ + c1l4; \
  vf4 g1_ = e1_ * kk_ + c1l4; \
  ssumL = u0_ + g0_; ssumH = u1_ + g1_; \
  betaL += ssumL; betaH += ssumH; \
  float* wp_ = stored + ((size_t)(unsigned)r_ << 9) + jb; \
  *(vf4*)wp_ = g0_; *(vf4*)(wp_ + 4) = g1_; \
  GA = g0_; GB = g1_; \
}

__global__ void __launch_bounds__(512, 1) sag_k(const float* __restrict__ D2,
                                                const int* __restrict__ idx,
                                                float* __restrict__ stored,
                                                float* __restrict__ beta_out) {
  const int tid = threadIdx.x;
  if (tid >= 64) {
    const vf4* c4 = (const vf4*)D2;
    const vf4* s4 = (const vf4*)stored;
    vf4 acc = {0.f, 0.f, 0.f, 0.f};
    for (int p = tid - 64; p < 65536; p += 448) { acc += c4[p]; acc += s4[p]; }
    float accs = acc.x + acc.y + acc.z + acc.w;
    asm volatile("" :: "v"(accs));
    return;
  }

  const int jb = tid * 8;
  const float C2NL = -0.0028177637f;                 // -(1/512)*log2e
  const vf4 c1l4 = {5.503574e-06f, 5.503574e-06f, 5.503574e-06f, 5.503574e-06f};

  vf4 z4 = {0.f, 0.f, 0.f, 0.f};
  vf4 betaL = z4, betaH = z4, ssumL = z4, ssumH = z4;
  vf4 h1A = z4, h1B = z4, h2A = z4, h2B = z4, h3A = z4, h3B = z4;
  vf4 h4A = z4, h4B = z4, h5A = z4, h5B = z4, h6A = z4, h6B = z4;
  int hr1 = -1, hr2 = -1, hr3 = -1, hr4 = -1, hr5 = -1, hr6 = -1;
  float vsh = 0.f;

  int i0 = RFL(idx[0]), i1 = RFL(idx[1]), i2 = RFL(idx[2]), i3 = RFL(idx[3]);
  int i4 = RFL(idx[4]), i5 = RFL(idx[5]), i6 = RFL(idx[6]), i7 = RFL(idx[7]);

  vf4 s0dA, s0dB, s0sA, s0sB, s1dA, s1dB, s1sA, s1sB;
  SLD0(i0);
  SLD1(i1);

  vf4 g0a, g0b, g1a, g1b, g2a, g2b, g3a, g3b;
  vf4 g4a, g4b, g5a, g5b, g6a, g6b, g7a, g7b;

  for (int t = 0; t < 1000; t += 8) {
    int tb = (t + 8 < 1000) ? (t + 8) : 992;
    int n0 = RFL(idx[tb + 0]), n1 = RFL(idx[tb + 1]);
    int n2 = RFL(idx[tb + 2]), n3 = RFL(idx[tb + 3]);
    int n4 = RFL(idx[tb + 4]), n5 = RFL(idx[tb + 5]);
    int n6 = RFL(idx[tb + 6]), n7 = RFL(idx[tb + 7]);

    STEP(i0, i2, s0dA, s0dB, s0sA, s0sB, SLD0,
         hr1,h1A,h1B, hr2,h2A,h2B, hr3,h3A,h3B, hr4,h4A,h4B, hr5,h5A,h5B, hr6,h6A,h6B,
         g0a, g0b)
    STEP(i1, i3, s1dA, s1dB, s1sA, s1sB, SLD1,
         i0,g0a,g0b, hr1,h1A,h1B, hr2,h2A,h2B, hr3,h3A,h3B, hr4,h4A,h4B, hr5,h5A,h5B,
         g1a, g1b)
    STEP(i2, i4, s0dA, s0dB, s0sA, s0sB, SLD0,
         i1,g1a,g1b, i0,g0a,g0b, hr1,h1A,h1B, hr2,h2A,h2B, hr3,h3A,h3B, hr4,h4A,h4B,
         g2a, g2b)
    STEP(i3, i5, s1dA, s1dB, s1sA, s1sB, SLD1,
         i2,g2a,g2b, i1,g1a,g1b, i0,g0a,g0b, hr1,h1A,h1B, hr2,h2A,h2B, hr3,h3A,h3B,
         g3a, g3b)
    STEP(i4, i6, s0dA, s0dB, s0sA, s0sB, SLD0,
         i3,g3a,g3b, i2,g2a,g2b, i1,g1a,g1b, i0,g0a,g0b, hr1,h1A,h1B, hr2,h2A,h2B,
         g4a, g4b)
    STEP(i5, i7, s1dA, s1dB, s1sA, s1sB, SLD1,
         i4,g4a,g4b, i3,g3a,g3b, i2,g2a,g2b, i1,g1a,g1b, i0,g0a,g0b, hr1,h1A,h1B,
         g5a, g5b)
    STEP(i6, n0, s0dA, s0dB, s0sA, s0sB, SLD0,
         i5,g5a,g5b, i4,g4a,g4b, i3,g3a,g3b, i2,g2a,g2b, i1,g1a,g1b, i0,g0a,g0b,
         g6a, g6b)
    STEP(i7, n1, s1dA, s1dB, s1sA, s1sB, SLD1,
         i6,g6a,g6b, i5,g5a,g5b, i4,g4a,g4b, i3,g3a,g3b, i2,g2a,g2b, i1,g1a,g1b,
         g7a, g7b)

    {
      vf4 qm;
      qm.x = fmaxf(betaL.x, betaH.x); qm.y = fmaxf(betaL.y, betaH.y);
      qm.z = fmaxf(betaL.z, betaH.z); qm.w = fmaxf(betaL.w, betaH.w);
      float lm = fmaxf(fmaxf(qm.x, qm.y), fmaxf(qm.z, qm.w));
      float dm = wmax64_l63(lm);
      betaL = betaL - dm; betaH = betaH - dm;
      vsh += dm;
    }

    hr1 = i7; h1A = g7a; h1B = g7b;
    hr2 = i6; h2A = g6a; h2B = g6b;
    hr3 = i5; h3A = g5a; h3B = g5b;
    hr4 = i4; h4A = g4a; h4B = g4b;
    hr5 = i3; h5A = g3a; h5B = g3b;
    hr6 = i2; h6A = g2a; h6B = g2b;
    i0 = n0; i1 = n1; i2 = n2; i3 = n3;
    i4 = n4; i5 = n5; i6 = n6; i7 = n7;
  }

  const float LN2 = 0.6931471805599453f;
  vf4 oL = (betaL + vsh) * LN2;
  vf4 oH = (betaH + vsh) * LN2;
  *(vf4*)(beta_out + jb) = oL;
  *(vf4*)(beta_out + jb + 4) = oH;
}

// ---------------- plan recovery + C output + entropy rows ----------------
__global__ void p_k(const float* __restrict__ craw, const float* __restrict__ sp,
                    const float* __restrict__ beta, float* __restrict__ P,
                    float* __restrict__ Cout, float* __restrict__ rowsum) {
  __shared__ float red[256];
  int i = blockIdx.x, tid = threadIdx.x;
  float c0 = craw[(size_t)i * 512 + tid];
  float c1 = craw[(size_t)i * 512 + tid + 256];
  float sp0 = sp[tid], sp1 = sp[tid + 256];
  float u0 = (beta[tid] - sp0) + c0;
  float u1 = (beta[tid + 256] - sp1) + c1;
  Cout[(size_t)i * 512 + tid] = sp0 - c0;
  Cout[(size_t)i * 512 + tid + 256] = sp1 - c1;
  float m = fmaxf(u0, u1);
  red[tid] = m;
  __syncthreads();
  for (int st = 128; st > 0; st >>= 1) {
    if (tid < st) red[tid] = fmaxf(red[tid], red[tid + st]);
    __syncthreads();
  }
  m = red[0];
  __syncthreads();
  float e0 = __expf(u0 - m), e1 = __expf(u1 - m);
  red[tid] = e0 + e1;
  __syncthreads();
  for (int st = 128; st > 0; st >>= 1) {
    if (tid < st) red[tid] += red[tid + st];
    __syncthreads();
  }
  float lse = m + logf(red[0]);
  __syncthreads();
  const float log512 = 6.238324625039508f;
  float p0 = __expf(u0 - lse) * (1.0f / 512.0f);
  float p1 = __expf(u1 - lse) * (1.0f / 512.0f);
  P[(size_t)i * 512 + tid] = p0;
  P[(size_t)i * 512 + tid + 256] = p1;
  float pl = p0 * (u0 - lse - log512) + p1 * (u1 - lse - log512);
  red[tid] = pl;
  __syncthreads();
  for (int st = 128; st > 0; st >>= 1) {
    if (tid < st) red[tid] += red[tid + st];
    __syncthreads();
  }
  if (tid == 0) rowsum[i] = red[0];
}

__global__ void kl_k(const float* __restrict__ rowsum, float* __restrict__ out_kl) {
  __shared__ float red[512];
  int tid = threadIdx.x;
  red[tid] = rowsum[tid];
  __syncthreads();
  for (int st = 256; st > 0; st >>= 1) {
    if (tid < st) red[tid] += red[tid + st];
    __syncthreads();
  }
  if (tid == 0) out_kl[0] = red[0] + 2.0f * 6.238324625039508f;
}

extern "C" void kernel_launch(void* const* d_in, const int* in_sizes, int n_in,
                              void* d_out, int out_size, void* d_ws, size_t ws_size,
                              hipStream_t stream) {
  const float* x = (const float*)d_in[0];
  const float* z = (const float*)d_in[1];
  const float* fc_w = (const float*)d_in[2];
  const float* fc_b = (const float*)d_in[3];
  const float* ct0_w = (const float*)d_in[4];
  const float* ct0_b = (const float*)d_in[5];
  const float* ct1_w = (const float*)d_in[6];
  const float* ct1_b = (const float*)d_in[7];
  const float* fct_w = (const float*)d_in[8];
  const float* fct_b = (const float*)d_in[9];
  const float* conv_w = (const float*)d_in[10];
  const float* conv_b = (const float*)d_in[11];
  const int* idx = (const int*)d_in[12];

  float* out = (float*)d_out;
  float* Pout = out;               // 512*512
  float* Cout = out + 262144;      // 512*512
  float* klout = out + 524288;     // 1

  float* ws = (float*)d_ws;
  float* h0 = ws;                       // 512*2048   (-> Craw after ct0)
  float* h1 = h0 + 1048576;             // 512*64*49  (-> D2 after ct1)
  float* h2 = h1 + 1605632;             // 512*32*196
  float* h3 = h2 + 3211264;             // 512*32*784
  float* logit = h3 + 12845056;         // 512*784
  float* sp = logit + 401408;           // 512
  float* beta = sp + 512;               // 512
  float* stored = beta + 512;           // 512*512
  float* rowsum = stored + 262144;      // 512
  float* Craw = h0;
  float* D2 = h1;

  hipMemsetAsync(stored, 0, 262144 * sizeof(float), stream);

  fc_relu_k<<<1024, 256, 0, stream>>>(z, fc_w, fc_b, h0);
  convt_pair_k<128, 64, 4, 7><<<dim3(16, 16), 256, 0, stream>>>(h0, ct0_w, ct0_b, h1);
  convt_pair_k<64, 32, 7, 14><<<dim3(49, 8), 256, 0, stream>>>(h1, ct1_w, ct1_b, h2);
  convt_pair_k<32, 32, 14, 28><<<dim3(196, 8), 256, 0, stream>>>(h2, fct_w, fct_b, h3);
  conv_final_pair_k<<<784, 256, 0, stream>>>(h3, conv_w, conv_b, logit);
  cost_k<<<dim3(8, 16), 256, 0, stream>>>(x, logit, Craw, sp);
  prep_k<<<512, 256, 0, stream>>>(Craw, sp, D2);
  sag_k<<<1, 512, 0, stream>>>(D2, idx, stored, beta);
  p_k<<<512, 256, 0, stream>>>(Craw, sp, beta, Pout, Cout, rowsum);
  kl_k<<<1, 512, 0, stream>>>(rowsum, klout);
}

// Round 15
// 527.053 us; speedup vs baseline: 1.6844x; 1.0061x over previous
//
#include <hip/hip_runtime.h>
#include <hip/hip_bf16.h>
#include <math.h>

// R14 pipeline (530us) minus 2 nodes:
//  - prep_k zeroes `stored` (was memset node) and inits klout = 2*log512
//  - p_k accumulates kl via one atomicAdd per block (kl_k node dropped)
//  - p_k/prep reduces via DPP wave-reduce + 4-partial LDS (3 syncs vs 24)

typedef float vf4 __attribute__((ext_vector_type(4)));

#define RFL(v) __builtin_amdgcn_readfirstlane(v)

// ---------------- FC ----------------
__global__ void fc_relu_k(const float* __restrict__ z, const float* __restrict__ w,
                          const float* __restrict__ b, float* __restrict__ out) {
  int n = blockIdx.x >> 1;
  int c0 = ((blockIdx.x & 1) << 10) + threadIdx.x * 4;
  const float* zr = z + n * 64;
  float4 acc = *(const float4*)&b[c0];
#pragma unroll
  for (int k = 0; k < 64; ++k) {
    float zk = zr[k];
    float4 wv = *(const float4*)&w[k * 2048 + c0];
    acc.x = fmaf(zk, wv.x, acc.x);
    acc.y = fmaf(zk, wv.y, acc.y);
    acc.z = fmaf(zk, wv.z, acc.z);
    acc.w = fmaf(zk, wv.w, acc.w);
  }
  acc.x = fmaxf(acc.x, 0.f); acc.y = fmaxf(acc.y, 0.f);
  acc.z = fmaxf(acc.z, 0.f); acc.w = fmaxf(acc.w, 0.f);
  *(float4*)&out[n * 2048 + c0] = acc;
}

// ---------------- ConvT (quad-gather, image-paired, GW=4) ----------------
#define TAPF4(T, P, XV0, XV1) { \
  float4 wv_ = *reinterpret_cast<const float4*>(&wt[((T) * CIN + ci) * 4]); \
  acc0[P][0] = fmaf(XV0, wv_.x, acc0[P][0]); \
  acc0[P][1] = fmaf(XV0, wv_.y, acc0[P][1]); \
  acc0[P][2] = fmaf(XV0, wv_.z, acc0[P][2]); \
  acc0[P][3] = fmaf(XV0, wv_.w, acc0[P][3]); \
  acc1[P][0] = fmaf(XV1, wv_.x, acc1[P][0]); \
  acc1[P][1] = fmaf(XV1, wv_.y, acc1[P][1]); \
  acc1[P][2] = fmaf(XV1, wv_.z, acc1[P][2]); \
  acc1[P][3] = fmaf(XV1, wv_.w, acc1[P][3]); }

template <int CIN, int COUT, int HIN, int HOUT>
__global__ void convt_pair_k(const float* __restrict__ x, const float* __restrict__ w,
                             const float* __restrict__ bias, float* __restrict__ y) {
  constexpr bool FULL = (HOUT == 2 * HIN);
  constexpr int QP = HIN * HIN;
  __shared__ float wt[9 * CIN * 4];
  const int tid = threadIdx.x;
  const int g4 = blockIdx.y * 4;
  for (int e = tid; e < 9 * CIN * 4; e += 256) {
    int cl = e & 3;
    int rest = e >> 2;
    int ci = rest & (CIN - 1);
    int t = rest / CIN;
    wt[e] = w[((size_t)ci * COUT + g4 + cl) * 9 + t];
  }
  __syncthreads();

  int q = blockIdx.x * 256 + tid;
  int np = q / QP;
  int pq = q % QP;
  int a = pq / HIN, b = pq % HIN;
  const bool oka = (a + 1 < HIN), okb = (b + 1 < HIN);
  const float* xim0 = x + (size_t)np * CIN * QP + a * HIN + b;
  const float* xim1 = x + (size_t)(np + 256) * CIN * QP + a * HIN + b;

  float acc0[4][4], acc1[4][4];
#pragma unroll
  for (int p = 0; p < 4; ++p)
#pragma unroll
    for (int c = 0; c < 4; ++c) { acc0[p][c] = 0.f; acc1[p][c] = 0.f; }

  for (int ci = 0; ci < CIN; ++ci) {
    const float* xc0 = xim0 + ci * QP;
    const float* xc1 = xim1 + ci * QP;
    float p00 = xc0[0];
    float p01 = okb ? xc0[1] : 0.f;
    float p10 = oka ? xc0[HIN] : 0.f;
    float p11 = (oka && okb) ? xc0[HIN + 1] : 0.f;
    float q00 = xc1[0];
    float q01 = okb ? xc1[1] : 0.f;
    float q10 = oka ? xc1[HIN] : 0.f;
    float q11 = (oka && okb) ? xc1[HIN + 1] : 0.f;
    TAPF4(4, 0, p00, q00)
    TAPF4(3, 1, p01, q01) TAPF4(5, 1, p00, q00)
    TAPF4(1, 2, p10, q10) TAPF4(7, 2, p00, q00)
    TAPF4(0, 3, p11, q11) TAPF4(2, 3, p10, q10) TAPF4(6, 3, p01, q01) TAPF4(8, 3, p00, q00)
  }

  int oh0 = 2 * a, ow0 = 2 * b;
  bool vh = FULL || (oh0 + 1 < HOUT);
  bool vw = FULL || (ow0 + 1 < HOUT);
#pragma unroll
  for (int c = 0; c < 4; ++c) {
    float bv = bias[g4 + c];
    float a00 = fmaxf(acc0[0][c] + bv, 0.f);
    float a01 = fmaxf(acc0[1][c] + bv, 0.f);
    float a10 = fmaxf(acc0[2][c] + bv, 0.f);
    float a11 = fmaxf(acc0[3][c] + bv, 0.f);
    float b00 = fmaxf(acc1[0][c] + bv, 0.f);
    float b01 = fmaxf(acc1[1][c] + bv, 0.f);
    float b10 = fmaxf(acc1[2][c] + bv, 0.f);
    float b11 = fmaxf(acc1[3][c] + bv, 0.f);
    float* yb0 = y + (((size_t)np * COUT + g4 + c) * HOUT + oh0) * (size_t)HOUT + ow0;
    float* yb1 = y + (((size_t)(np + 256) * COUT + g4 + c) * HOUT + oh0) * (size_t)HOUT + ow0;
    if (FULL) {
      *(float2*)yb0 = make_float2(a00, a01);
      *(float2*)(yb0 + HOUT) = make_float2(a10, a11);
      *(float2*)yb1 = make_float2(b00, b01);
      *(float2*)(yb1 + HOUT) = make_float2(b10, b11);
    } else {
      yb0[0] = a00;
      yb1[0] = b00;
      if (vw) { yb0[1] = a01; yb1[1] = b01; }
      if (vh) { yb0[HOUT] = a10; yb1[HOUT] = b10; }
      if (vh && vw) { yb0[HOUT + 1] = a11; yb1[HOUT + 1] = b11; }
    }
  }
}

// ---------------- final 32->1 conv (image-paired) ----------------
__global__ void conv_final_pair_k(const float* __restrict__ x, const float* __restrict__ w,
                                  const float* __restrict__ bias, float* __restrict__ y) {
  __shared__ float ws_[288];
  int tid = threadIdx.x;
  if (tid < 288) ws_[tid] = w[tid];
  __syncthreads();
  int gid = blockIdx.x * 256 + tid;
  int px = gid % 784;
  int np = gid / 784;
  int ow = px % 28;
  int oh = px / 28;
  bool h0 = oh > 0, h2 = oh < 27, w0 = ow > 0, w2 = ow < 27;
  const float* xb0 = x + (size_t)np * 32 * 784 + (oh - 1) * 28 + (ow - 1);
  const float* xb1 = x + (size_t)(np + 256) * 32 * 784 + (oh - 1) * 28 + (ow - 1);
  float acc0 = bias[0], acc1 = bias[0];
  for (int ci = 0; ci < 32; ++ci) {
    const float* xc0 = xb0 + ci * 784;
    const float* xc1 = xb1 + ci * 784;
    const float* wc = &ws_[ci * 9];
    if (h0 && w0) { acc0 = fmaf(xc0[0], wc[0], acc0); acc1 = fmaf(xc1[0], wc[0], acc1); }
    if (h0)       { acc0 = fmaf(xc0[1], wc[1], acc0); acc1 = fmaf(xc1[1], wc[1], acc1); }
    if (h0 && w2) { acc0 = fmaf(xc0[2], wc[2], acc0); acc1 = fmaf(xc1[2], wc[2], acc1); }
    if (w0)       { acc0 = fmaf(xc0[28], wc[3], acc0); acc1 = fmaf(xc1[28], wc[3], acc1); }
                    acc0 = fmaf(xc0[29], wc[4], acc0); acc1 = fmaf(xc1[29], wc[4], acc1);
    if (w2)       { acc0 = fmaf(xc0[30], wc[5], acc0); acc1 = fmaf(xc1[30], wc[5], acc1); }
    if (h2 && w0) { acc0 = fmaf(xc0[56], wc[6], acc0); acc1 = fmaf(xc1[56], wc[6], acc1); }
    if (h2)       { acc0 = fmaf(xc0[57], wc[7], acc0); acc1 = fmaf(xc1[57], wc[7], acc1); }
    if (h2 && w2) { acc0 = fmaf(xc0[58], wc[8], acc0); acc1 = fmaf(xc1[58], wc[8], acc1); }
  }
  y[(size_t)np * 784 + px] = acc0;
  y[(size_t)(np + 256) * 784 + px] = acc1;
}

// ---------------- cross-lane helpers ----------------
template <int CTRL>
__device__ __forceinline__ float dpp_f(float x) {
  return __int_as_float(__builtin_amdgcn_update_dpp(0, __float_as_int(x), CTRL, 0xF, 0xF, true));
}
__device__ __forceinline__ float rdl(float v, int l) {
  return __int_as_float(__builtin_amdgcn_readlane(__float_as_int(v), l));
}
__device__ __forceinline__ float wsum64_l63(float v) {
  v += dpp_f<0xB1>(v);
  v += dpp_f<0x4E>(v);
  v += dpp_f<0x141>(v);
  v += dpp_f<0x140>(v);
  v += dpp_f<0x142>(v);
  v += dpp_f<0x143>(v);
  return rdl(v, 63);
}
__device__ __forceinline__ float wmax64_l63(float v) {
  v = fmaxf(v, dpp_f<0xB1>(v));
  v = fmaxf(v, dpp_f<0x4E>(v));
  v = fmaxf(v, dpp_f<0x141>(v));
  v = fmaxf(v, dpp_f<0x140>(v));
  v = fmaxf(v, dpp_f<0x142>(v));
  v = fmaxf(v, dpp_f<0x143>(v));
  return rdl(v, 63);
}

// ---------------- cost GEMM 32x64 + fused softplus row sums ----------------
__global__ void cost_k(const float* __restrict__ X, const float* __restrict__ L,
                       float* __restrict__ Craw, float* __restrict__ sp) {
  __shared__ float Xs[16][36];
  __shared__ float Ls[16][68];
  int tid = threadIdx.x;
  int i0 = blockIdx.y * 32, j0 = blockIdx.x * 64;
  int lrow = tid >> 2;
  int lq = tid & 3;
  int xrow = tid & 31;
  int xq = (tid >> 5) & 3;
  bool doX = tid < 128;
  bool doSP = (blockIdx.y == 0);
  int tx = tid & 15, ty = tid >> 4;
  float acc[2][4] = {};
  float spacc = 0.f;
  for (int k0 = 0; k0 < 784; k0 += 16) {
    float4 lv = *(const float4*)&L[(size_t)(j0 + lrow) * 784 + k0 + lq * 4];
    float4 xv = {0.f, 0.f, 0.f, 0.f};
    if (doX) xv = *(const float4*)&X[(size_t)(i0 + xrow) * 784 + k0 + xq * 4];
    __syncthreads();
    Ls[lq * 4 + 0][lrow] = lv.x; Ls[lq * 4 + 1][lrow] = lv.y;
    Ls[lq * 4 + 2][lrow] = lv.z; Ls[lq * 4 + 3][lrow] = lv.w;
    if (doX) {
      Xs[xq * 4 + 0][xrow] = xv.x; Xs[xq * 4 + 1][xrow] = xv.y;
      Xs[xq * 4 + 2][xrow] = xv.z; Xs[xq * 4 + 3][xrow] = xv.w;
    }
    if (doSP) {
      spacc += fmaxf(lv.x, 0.f) + log1pf(__expf(-fabsf(lv.x)));
      spacc += fmaxf(lv.y, 0.f) + log1pf(__expf(-fabsf(lv.y)));
      spacc += fmaxf(lv.z, 0.f) + log1pf(__expf(-fabsf(lv.z)));
      spacc += fmaxf(lv.w, 0.f) + log1pf(__expf(-fabsf(lv.w)));
    }
    __syncthreads();
#pragma unroll
    for (int k = 0; k < 16; ++k) {
      float2 a = *(const float2*)&Xs[k][ty * 2];
      float4 bq = *(const float4*)&Ls[k][tx * 4];
      acc[0][0] = fmaf(a.x, bq.x, acc[0][0]); acc[0][1] = fmaf(a.x, bq.y, acc[0][1]);
      acc[0][2] = fmaf(a.x, bq.z, acc[0][2]); acc[0][3] = fmaf(a.x, bq.w, acc[0][3]);
      acc[1][0] = fmaf(a.y, bq.x, acc[1][0]); acc[1][1] = fmaf(a.y, bq.y, acc[1][1]);
      acc[1][2] = fmaf(a.y, bq.z, acc[1][2]); acc[1][3] = fmaf(a.y, bq.w, acc[1][3]);
    }
  }
#pragma unroll
  for (int r = 0; r < 2; ++r) {
    float4 o = make_float4(acc[r][0], acc[r][1], acc[r][2], acc[r][3]);
    *(float4*)&Craw[(size_t)(i0 + ty * 2 + r) * 512 + j0 + tx * 4] = o;
  }
  if (doSP) {
    float q = spacc;
    q += dpp_f<0xB1>(q);
    q += dpp_f<0x4E>(q);
    if (lq == 0) sp[j0 + lrow] = q;
  }
}

// ---------------- prep: rowmax (DPP) + shifted/log2e cost + zero stored + init kl ----------------
__global__ void prep_k(const float* __restrict__ craw, const float* __restrict__ sp,
                       float* __restrict__ D2, float* __restrict__ stored,
                       float* __restrict__ klout) {
  __shared__ float part[4];
  int i = blockIdx.x, tid = threadIdx.x;
  int wid = tid >> 6, lane = tid & 63;
  // zero stored (replaces memset node)
  stored[(size_t)i * 512 + tid] = 0.f;
  stored[(size_t)i * 512 + tid + 256] = 0.f;
  if (i == 0 && tid == 0) klout[0] = 12.476649250079016f;   // 2*log512
  float c0 = craw[(size_t)i * 512 + tid];
  float c1 = craw[(size_t)i * 512 + tid + 256];
  float v0 = c0 - sp[tid];
  float v1 = c1 - sp[tid + 256];
  float wm = wmax64_l63(fmaxf(v0, v1));
  if (lane == 0) part[wid] = wm;
  __syncthreads();
  float m = fmaxf(fmaxf(part[0], part[1]), fmaxf(part[2], part[3]));
  const float L2E = 1.4426950408889634f;
  D2[(size_t)i * 512 + tid] = (m - v0) * L2E;
  D2[(size_t)i * 512 + tid + 256] = (m - v1) * L2E;
}

// ---------------- SAG scan (single wave; R13-proven) ----------------
#define SLD0(ROW) { const float* cp_ = D2 + ((size_t)(unsigned)(ROW) << 9) + jb; \
  s0dA = *(const vf4*)cp_; s0dB = *(const vf4*)(cp_ + 4); \
  const float* tp_ = stored + ((size_t)(unsigned)(ROW) << 9) + jb; \
  s0sA = *(const vf4*)tp_; s0sB = *(const vf4*)(tp_ + 4); }
#define SLD1(ROW) { const float* cp_ = D2 + ((size_t)(unsigned)(ROW) << 9) + jb; \
  s1dA = *(const vf4*)cp_; s1dB = *(const vf4*)(cp_ + 4); \
  const float* tp_ = stored + ((size_t)(unsigned)(ROW) << 9) + jb; \
  s1sA = *(const vf4*)tp_; s1sB = *(const vf4*)(tp_ + 4); }

#define STEP(RR, PFR, DA, DB, SA, SB, LDM, \
             R1,A1,B1, R2,A2,B2, R3,A3,B3, R4,A4,B4, R5,A5,B5, R6,A6,B6, \
             GA, GB) \
{ \
  vf4 d0_ = DA, d1_ = DB, t0_ = SA, t1_ = SB; \
  LDM(PFR); \
  const int r_ = (RR); \
  if (__builtin_expect((r_==(R1)) | (r_==(R2)) | (r_==(R3)) | \
                       (r_==(R4)) | (r_==(R5)) | (r_==(R6)), 0)) { \
    if (r_==(R6)) { t0_ = A6; t1_ = B6; } \
    if (r_==(R5)) { t0_ = A5; t1_ = B5; } \
    if (r_==(R4)) { t0_ = A4; t1_ = B4; } \
    if (r_==(R3)) { t0_ = A3; t1_ = B3; } \
    if (r_==(R2)) { t0_ = A2; t1_ = B2; } \
    if (r_==(R1)) { t0_ = A1; t1_ = B1; } \
  } \
  vf4 u0_ = ssumL - t0_; \
  vf4 u1_ = ssumH - t1_; \
  vf4 a0_ = betaL - d0_; \
  vf4 a1_ = betaH - d1_; \
  vf4 e0_, e1_; \
  e0_.x = __builtin_amdgcn_exp2f(a0_.x); e0_.y = __builtin_amdgcn_exp2f(a0_.y); \
  e0_.z = __builtin_amdgcn_exp2f(a0_.z); e0_.w = __builtin_amdgcn_exp2f(a0_.w); \
  e1_.x = __builtin_amdgcn_exp2f(a1_.x); e1_.y = __builtin_amdgcn_exp2f(a1_.y); \
  e1_.z = __builtin_amdgcn_exp2f(a1_.z); e1_.w = __builtin_amdgcn_exp2f(a1_.w); \
  vf4 es_ = e0_ + e1_; \
  float S_ = wsum64_l63((es_.x + es_.z) + (es_.y + es_.w)); \
  S_ = fmaxf(S_, 1e-35f); \
  float kk_ = C2NL * __builtin_amdgcn_rcpf(S_); \
  vf4 g0_ = e0_ * kk_ + c1l4; \
  vf4 g1_ = e1_ * kk_ + c1l4; \
  ssumL = u0_ + g0_; ssumH = u1_ + g1_; \
  betaL += ssumL; betaH += ssumH; \
  float* wp_ = stored + ((size_t)(unsigned)r_ << 9) + jb; \
  *(vf4*)wp_ = g0_; *(vf4*)(wp_ + 4) = g1_; \
  GA = g0_; GB = g1_; \
}

__global__ void __launch_bounds__(512, 1) sag_k(const float* __restrict__ D2,
                                                const int* __restrict__ idx,
                                                float* __restrict__ stored,
                                                float* __restrict__ beta_out) {
  const int tid = threadIdx.x;
  if (tid >= 64) {
    const vf4* c4 = (const vf4*)D2;
    const vf4* s4 = (const vf4*)stored;
    vf4 acc = {0.f, 0.f, 0.f, 0.f};
    for (int p = tid - 64; p < 65536; p += 448) { acc += c4[p]; acc += s4[p]; }
    float accs = acc.x + acc.y + acc.z + acc.w;
    asm volatile("" :: "v"(accs));
    return;
  }

  const int jb = tid * 8;
  const float C2NL = -0.0028177637f;                 // -(1/512)*log2e
  const vf4 c1l4 = {5.503574e-06f, 5.503574e-06f, 5.503574e-06f, 5.503574e-06f};

  vf4 z4 = {0.f, 0.f, 0.f, 0.f};
  vf4 betaL = z4, betaH = z4, ssumL = z4, ssumH = z4;
  vf4 h1A = z4, h1B = z4, h2A = z4, h2B = z4, h3A = z4, h3B = z4;
  vf4 h4A = z4, h4B = z4, h5A = z4, h5B = z4, h6A = z4, h6B = z4;
  int hr1 = -1, hr2 = -1, hr3 = -1, hr4 = -1, hr5 = -1, hr6 = -1;
  float vsh = 0.f;

  int i0 = RFL(idx[0]), i1 = RFL(idx[1]), i2 = RFL(idx[2]), i3 = RFL(idx[3]);
  int i4 = RFL(idx[4]), i5 = RFL(idx[5]), i6 = RFL(idx[6]), i7 = RFL(idx[7]);

  vf4 s0dA, s0dB, s0sA, s0sB, s1dA, s1dB, s1sA, s1sB;
  SLD0(i0);
  SLD1(i1);

  vf4 g0a, g0b, g1a, g1b, g2a, g2b, g3a, g3b;
  vf4 g4a, g4b, g5a, g5b, g6a, g6b, g7a, g7b;

  for (int t = 0; t < 1000; t += 8) {
    int tb = (t + 8 < 1000) ? (t + 8) : 992;
    int n0 = RFL(idx[tb + 0]), n1 = RFL(idx[tb + 1]);
    int n2 = RFL(idx[tb + 2]), n3 = RFL(idx[tb + 3]);
    int n4 = RFL(idx[tb + 4]), n5 = RFL(idx[tb + 5]);
    int n6 = RFL(idx[tb + 6]), n7 = RFL(idx[tb + 7]);

    STEP(i0, i2, s0dA, s0dB, s0sA, s0sB, SLD0,
         hr1,h1A,h1B, hr2,h2A,h2B, hr3,h3A,h3B, hr4,h4A,h4B, hr5,h5A,h5B, hr6,h6A,h6B,
         g0a, g0b)
    STEP(i1, i3, s1dA, s1dB, s1sA, s1sB, SLD1,
         i0,g0a,g0b, hr1,h1A,h1B, hr2,h2A,h2B, hr3,h3A,h3B, hr4,h4A,h4B, hr5,h5A,h5B,
         g1a, g1b)
    STEP(i2, i4, s0dA, s0dB, s0sA, s0sB, SLD0,
         i1,g1a,g1b, i0,g0a,g0b, hr1,h1A,h1B, hr2,h2A,h2B, hr3,h3A,h3B, hr4,h4A,h4B,
         g2a, g2b)
    STEP(i3, i5, s1dA, s1dB, s1sA, s1sB, SLD1,
         i2,g2a,g2b, i1,g1a,g1b, i0,g0a,g0b, hr1,h1A,h1B, hr2,h2A,h2B, hr3,h3A,h3B,
         g3a, g3b)
    STEP(i4, i6, s0dA, s0dB, s0sA, s0sB, SLD0,
         i3,g3a,g3b, i2,g2a,g2b, i1,g1a,g1b, i0,g0a,g0b, hr1,h1A,h1B, hr2,h2A,h2B,
         g4a, g4b)
    STEP(i5, i7, s1dA, s1dB, s1sA, s1sB, SLD1,
         i4,g4a,g4b, i3,g3a,g3b, i2,g2a,g2b, i1,g1a,g1b, i0,g0a,g0b, hr1,h1A,h1B,
         g5a, g5b)
    STEP(i6, n0, s0dA, s0dB, s0sA, s0sB, SLD0,
         i5,g5a,g5b, i4,g4a,g4b, i3,g3a,g3b, i2,g2a,g2b, i1,g1a,g1b, i0,g0a,g0b,
         g6a, g6b)
    STEP(i7, n1, s1dA, s1dB, s1sA, s1sB, SLD1,
         i6,g6a,g6b, i5,g5a,g5b, i4,g4a,g4b, i3,g3a,g3b, i2,g2a,g2b, i1,g1a,g1b,
         g7a, g7b)

    {
      vf4 qm;
      qm.x = fmaxf(betaL.x, betaH.x); qm.y = fmaxf(betaL.y, betaH.y);
      qm.z = fmaxf(betaL.z, betaH.z); qm.w = fmaxf(betaL.w, betaH.w);
      float lm = fmaxf(fmaxf(qm.x, qm.y), fmaxf(qm.z, qm.w));
      float dm = wmax64_l63(lm);
      betaL = betaL - dm; betaH = betaH - dm;
      vsh += dm;
    }

    hr1 = i7; h1A = g7a; h1B = g7b;
    hr2 = i6; h2A = g6a; h2B = g6b;
    hr3 = i5; h3A = g5a; h3B = g5b;
    hr4 = i4; h4A = g4a; h4B = g4b;
    hr5 = i3; h5A = g3a; h5B = g3b;
    hr6 = i2; h6A = g2a; h6B = g2b;
    i0 = n0; i1 = n1; i2 = n2; i3 = n3;
    i4 = n4; i5 = n5; i6 = n6; i7 = n7;
  }

  const float LN2 = 0.6931471805599453f;
  vf4 oL = (betaL + vsh) * LN2;
  vf4 oH = (betaH + vsh) * LN2;
  *(vf4*)(beta_out + jb) = oL;
  *(vf4*)(beta_out + jb + 4) = oH;
}

// ---------------- plan recovery + C output + entropy + kl atomic ----------------
__global__ void p_k(const float* __restrict__ craw, const float* __restrict__ sp,
                    const float* __restrict__ beta, float* __restrict__ P,
                    float* __restrict__ Cout, float* __restrict__ klout) {
  __shared__ float part[12];
  int i = blockIdx.x, tid = threadIdx.x;
  int wid = tid >> 6, lane = tid & 63;
  float c0 = craw[(size_t)i * 512 + tid];
  float c1 = craw[(size_t)i * 512 + tid + 256];
  float sp0 = sp[tid], sp1 = sp[tid + 256];
  float u0 = (beta[tid] - sp0) + c0;
  float u1 = (beta[tid + 256] - sp1) + c1;
  Cout[(size_t)i * 512 + tid] = sp0 - c0;
  Cout[(size_t)i * 512 + tid + 256] = sp1 - c1;
  float wm = wmax64_l63(fmaxf(u0, u1));
  if (lane == 0) part[wid] = wm;
  __syncthreads();
  float m = fmaxf(fmaxf(part[0], part[1]), fmaxf(part[2], part[3]));
  float e0 = __expf(u0 - m), e1 = __expf(u1 - m);
  float ws = wsum64_l63(e0 + e1);
  if (lane == 0) part[4 + wid] = ws;
  __syncthreads();
  float S = (part[4] + part[5]) + (part[6] + part[7]);
  float lse = m + logf(S);
  const float log512 = 6.238324625039508f;
  float p0 = __expf(u0 - lse) * (1.0f / 512.0f);
  float p1 = __expf(u1 - lse) * (1.0f / 512.0f);
  P[(size_t)i * 512 + tid] = p0;
  P[(size_t)i * 512 + tid + 256] = p1;
  float pl = p0 * (u0 - lse - log512) + p1 * (u1 - lse - log512);
  float wp = wsum64_l63(pl);
  if (lane == 0) part[8 + wid] = wp;
  __syncthreads();
  if (tid == 0)
    atomicAdd(klout, (part[8] + part[9]) + (part[10] + part[11]));
}

extern "C" void kernel_launch(void* const* d_in, const int* in_sizes, int n_in,
                              void* d_out, int out_size, void* d_ws, size_t ws_size,
                              hipStream_t stream) {
  const float* x = (const float*)d_in[0];
  const float* z = (const float*)d_in[1];
  const float* fc_w = (const float*)d_in[2];
  const float* fc_b = (const float*)d_in[3];
  const float* ct0_w = (const float*)d_in[4];
  const float* ct0_b = (const float*)d_in[5];
  const float* ct1_w = (const float*)d_in[6];
  const float* ct1_b = (const float*)d_in[7];
  const float* fct_w = (const float*)d_in[8];
  const float* fct_b = (const float*)d_in[9];
  const float* conv_w = (const float*)d_in[10];
  const float* conv_b = (const float*)d_in[11];
  const int* idx = (const int*)d_in[12];

  float* out = (float*)d_out;
  float* Pout = out;               // 512*512
  float* Cout = out + 262144;      // 512*512
  float* klout = out + 524288;     // 1

  float* ws = (float*)d_ws;
  float* h0 = ws;                       // 512*2048   (-> Craw after ct0)
  float* h1 = h0 + 1048576;             // 512*64*49  (-> D2 after ct1)
  float* h2 = h1 + 1605632;             // 512*32*196
  float* h3 = h2 + 3211264;             // 512*32*784
  float* logit = h3 + 12845056;         // 512*784
  float* sp = logit + 401408;           // 512
  float* beta = sp + 512;               // 512
  float* stored = beta + 512;           // 512*512
  float* Craw = h0;
  float* D2 = h1;

  fc_relu_k<<<1024, 256, 0, stream>>>(z, fc_w, fc_b, h0);
  convt_pair_k<128, 64, 4, 7><<<dim3(16, 16), 256, 0, stream>>>(h0, ct0_w, ct0_b, h1);
  convt_pair_k<64, 32, 7, 14><<<dim3(49, 8), 256, 0, stream>>>(h1, ct1_w, ct1_b, h2);
  convt_pair_k<32, 32, 14, 28><<<dim3(196, 8), 256, 0, stream>>>(h2, fct_w, fct_b, h3);
  conv_final_pair_k<<<784, 256, 0, stream>>>(h3, conv_w, conv_b, logit);
  cost_k<<<dim3(8, 16), 256, 0, stream>>>(x, logit, Craw, sp);
  prep_k<<<512, 256, 0, stream>>>(Craw, sp, D2, stored, klout);
  sag_k<<<1, 512, 0, stream>>>(D2, idx, stored, beta);
  p_k<<<512, 256, 0, stream>>>(Craw, sp, beta, Pout, Cout, klout);
}

// Round 16
// 506.619 us; speedup vs baseline: 1.7524x; 1.0403x over previous
//
#include <hip/hip_runtime.h>
#include <hip/hip_bf16.h>
#include <math.h>

// R15 pipeline (527us) with widened small grids:
//  ct0: GW=2 -> 512 blocks (was 256 = 1/CU);  ct1: GW=2 -> 784 blocks (was 392)
//  cost: 16-row i-tiles -> 256 blocks (was 128 = half the CUs idle)
// Conv per-output fma order unchanged -> bitwise-identical decoder outputs.

typedef float vf4 __attribute__((ext_vector_type(4)));

#define RFL(v) __builtin_amdgcn_readfirstlane(v)

// ---------------- FC ----------------
__global__ void fc_relu_k(const float* __restrict__ z, const float* __restrict__ w,
                          const float* __restrict__ b, float* __restrict__ out) {
  int n = blockIdx.x >> 1;
  int c0 = ((blockIdx.x & 1) << 10) + threadIdx.x * 4;
  const float* zr = z + n * 64;
  float4 acc = *(const float4*)&b[c0];
#pragma unroll
  for (int k = 0; k < 64; ++k) {
    float zk = zr[k];
    float4 wv = *(const float4*)&w[k * 2048 + c0];
    acc.x = fmaf(zk, wv.x, acc.x);
    acc.y = fmaf(zk, wv.y, acc.y);
    acc.z = fmaf(zk, wv.z, acc.z);
    acc.w = fmaf(zk, wv.w, acc.w);
  }
  acc.x = fmaxf(acc.x, 0.f); acc.y = fmaxf(acc.y, 0.f);
  acc.z = fmaxf(acc.z, 0.f); acc.w = fmaxf(acc.w, 0.f);
  *(float4*)&out[n * 2048 + c0] = acc;
}

// ---------------- ConvT (quad-gather, image-paired, templated GW) ----------------
template <int CIN, int COUT, int HIN, int HOUT, int GW>
__global__ void convt_pair_k(const float* __restrict__ x, const float* __restrict__ w,
                             const float* __restrict__ bias, float* __restrict__ y) {
  constexpr bool FULL = (HOUT == 2 * HIN);
  constexpr int QP = HIN * HIN;
  __shared__ float wt[9 * CIN * GW];
  const int tid = threadIdx.x;
  const int g0 = blockIdx.y * GW;
  for (int e = tid; e < 9 * CIN * GW; e += 256) {
    int cl = e % GW;
    int rest = e / GW;
    int ci = rest & (CIN - 1);
    int t = rest / CIN;
    wt[e] = w[((size_t)ci * COUT + g0 + cl) * 9 + t];
  }
  __syncthreads();

  int q = blockIdx.x * 256 + tid;
  int np = q / QP;
  int pq = q % QP;
  int a = pq / HIN, b = pq % HIN;
  const bool oka = (a + 1 < HIN), okb = (b + 1 < HIN);
  const float* xim0 = x + (size_t)np * CIN * QP + a * HIN + b;
  const float* xim1 = x + (size_t)(np + 256) * CIN * QP + a * HIN + b;

  float acc0[4][GW], acc1[4][GW];
#pragma unroll
  for (int p = 0; p < 4; ++p)
#pragma unroll
    for (int c = 0; c < GW; ++c) { acc0[p][c] = 0.f; acc1[p][c] = 0.f; }

#define TAPW(T, P, XV0, XV1) { \
  if constexpr (GW == 4) { \
    float4 wv_ = *reinterpret_cast<const float4*>(&wt[((T) * CIN + ci) * 4]); \
    acc0[P][0] = fmaf(XV0, wv_.x, acc0[P][0]); \
    acc0[P][1] = fmaf(XV0, wv_.y, acc0[P][1]); \
    acc0[P][2] = fmaf(XV0, wv_.z, acc0[P][2]); \
    acc0[P][3] = fmaf(XV0, wv_.w, acc0[P][3]); \
    acc1[P][0] = fmaf(XV1, wv_.x, acc1[P][0]); \
    acc1[P][1] = fmaf(XV1, wv_.y, acc1[P][1]); \
    acc1[P][2] = fmaf(XV1, wv_.z, acc1[P][2]); \
    acc1[P][3] = fmaf(XV1, wv_.w, acc1[P][3]); \
  } else { \
    float2 wv_ = *reinterpret_cast<const float2*>(&wt[((T) * CIN + ci) * 2]); \
    acc0[P][0] = fmaf(XV0, wv_.x, acc0[P][0]); \
    acc0[P][1] = fmaf(XV0, wv_.y, acc0[P][1]); \
    acc1[P][0] = fmaf(XV1, wv_.x, acc1[P][0]); \
    acc1[P][1] = fmaf(XV1, wv_.y, acc1[P][1]); \
  } }

  for (int ci = 0; ci < CIN; ++ci) {
    const float* xc0 = xim0 + ci * QP;
    const float* xc1 = xim1 + ci * QP;
    float p00 = xc0[0];
    float p01 = okb ? xc0[1] : 0.f;
    float p10 = oka ? xc0[HIN] : 0.f;
    float p11 = (oka && okb) ? xc0[HIN + 1] : 0.f;
    float q00 = xc1[0];
    float q01 = okb ? xc1[1] : 0.f;
    float q10 = oka ? xc1[HIN] : 0.f;
    float q11 = (oka && okb) ? xc1[HIN + 1] : 0.f;
    TAPW(4, 0, p00, q00)
    TAPW(3, 1, p01, q01) TAPW(5, 1, p00, q00)
    TAPW(1, 2, p10, q10) TAPW(7, 2, p00, q00)
    TAPW(0, 3, p11, q11) TAPW(2, 3, p10, q10) TAPW(6, 3, p01, q01) TAPW(8, 3, p00, q00)
  }
#undef TAPW

  int oh0 = 2 * a, ow0 = 2 * b;
  bool vh = FULL || (oh0 + 1 < HOUT);
  bool vw = FULL || (ow0 + 1 < HOUT);
#pragma unroll
  for (int c = 0; c < GW; ++c) {
    float bv = bias[g0 + c];
    float a00 = fmaxf(acc0[0][c] + bv, 0.f);
    float a01 = fmaxf(acc0[1][c] + bv, 0.f);
    float a10 = fmaxf(acc0[2][c] + bv, 0.f);
    float a11 = fmaxf(acc0[3][c] + bv, 0.f);
    float b00 = fmaxf(acc1[0][c] + bv, 0.f);
    float b01 = fmaxf(acc1[1][c] + bv, 0.f);
    float b10 = fmaxf(acc1[2][c] + bv, 0.f);
    float b11 = fmaxf(acc1[3][c] + bv, 0.f);
    float* yb0 = y + (((size_t)np * COUT + g0 + c) * HOUT + oh0) * (size_t)HOUT + ow0;
    float* yb1 = y + (((size_t)(np + 256) * COUT + g0 + c) * HOUT + oh0) * (size_t)HOUT + ow0;
    if (FULL) {
      *(float2*)yb0 = make_float2(a00, a01);
      *(float2*)(yb0 + HOUT) = make_float2(a10, a11);
      *(float2*)yb1 = make_float2(b00, b01);
      *(float2*)(yb1 + HOUT) = make_float2(b10, b11);
    } else {
      yb0[0] = a00;
      yb1[0] = b00;
      if (vw) { yb0[1] = a01; yb1[1] = b01; }
      if (vh) { yb0[HOUT] = a10; yb1[HOUT] = b10; }
      if (vh && vw) { yb0[HOUT + 1] = a11; yb1[HOUT + 1] = b11; }
    }
  }
}

// ---------------- final 32->1 conv (image-paired) ----------------
__global__ void conv_final_pair_k(const float* __restrict__ x, const float* __restrict__ w,
                                  const float* __restrict__ bias, float* __restrict__ y) {
  __shared__ float ws_[288];
  int tid = threadIdx.x;
  if (tid < 288) ws_[tid] = w[tid];
  __syncthreads();
  int gid = blockIdx.x * 256 + tid;
  int px = gid % 784;
  int np = gid / 784;
  int ow = px % 28;
  int oh = px / 28;
  bool h0 = oh > 0, h2 = oh < 27, w0 = ow > 0, w2 = ow < 27;
  const float* xb0 = x + (size_t)np * 32 * 784 + (oh - 1) * 28 + (ow - 1);
  const float* xb1 = x + (size_t)(np + 256) * 32 * 784 + (oh - 1) * 28 + (ow - 1);
  float acc0 = bias[0], acc1 = bias[0];
  for (int ci = 0; ci < 32; ++ci) {
    const float* xc0 = xb0 + ci * 784;
    const float* xc1 = xb1 + ci * 784;
    const float* wc = &ws_[ci * 9];
    if (h0 && w0) { acc0 = fmaf(xc0[0], wc[0], acc0); acc1 = fmaf(xc1[0], wc[0], acc1); }
    if (h0)       { acc0 = fmaf(xc0[1], wc[1], acc0); acc1 = fmaf(xc1[1], wc[1], acc1); }
    if (h0 && w2) { acc0 = fmaf(xc0[2], wc[2], acc0); acc1 = fmaf(xc1[2], wc[2], acc1); }
    if (w0)       { acc0 = fmaf(xc0[28], wc[3], acc0); acc1 = fmaf(xc1[28], wc[3], acc1); }
                    acc0 = fmaf(xc0[29], wc[4], acc0); acc1 = fmaf(xc1[29], wc[4], acc1);
    if (w2)       { acc0 = fmaf(xc0[30], wc[5], acc0); acc1 = fmaf(xc1[30], wc[5], acc1); }
    if (h2 && w0) { acc0 = fmaf(xc0[56], wc[6], acc0); acc1 = fmaf(xc1[56], wc[6], acc1); }
    if (h2)       { acc0 = fmaf(xc0[57], wc[7], acc0); acc1 = fmaf(xc1[57], wc[7], acc1); }
    if (h2 && w2) { acc0 = fmaf(xc0[58], wc[8], acc0); acc1 = fmaf(xc1[58], wc[8], acc1); }
  }
  y[(size_t)np * 784 + px] = acc0;
  y[(size_t)(np + 256) * 784 + px] = acc1;
}

// ---------------- cross-lane helpers ----------------
template <int CTRL>
__device__ __forceinline__ float dpp_f(float x) {
  return __int_as_float(__builtin_amdgcn_update_dpp(0, __float_as_int(x), CTRL, 0xF, 0xF, true));
}
__device__ __forceinline__ float rdl(float v, int l) {
  return __int_as_float(__builtin_amdgcn_readlane(__float_as_int(v), l));
}
__device__ __forceinline__ float wsum64_l63(float v) {
  v += dpp_f<0xB1>(v);
  v += dpp_f<0x4E>(v);
  v += dpp_f<0x141>(v);
  v += dpp_f<0x140>(v);
  v += dpp_f<0x142>(v);
  v += dpp_f<0x143>(v);
  return rdl(v, 63);
}
__device__ __forceinline__ float wmax64_l63(float v) {
  v = fmaxf(v, dpp_f<0xB1>(v));
  v = fmaxf(v, dpp_f<0x4E>(v));
  v = fmaxf(v, dpp_f<0x141>(v));
  v = fmaxf(v, dpp_f<0x140>(v));
  v = fmaxf(v, dpp_f<0x142>(v));
  v = fmaxf(v, dpp_f<0x143>(v));
  return rdl(v, 63);
}

// ---------------- cost GEMM 16x64 tiles (256 blocks) + fused softplus ----------------
__global__ void cost_k(const float* __restrict__ X, const float* __restrict__ L,
                       float* __restrict__ Craw, float* __restrict__ sp) {
  __shared__ float Xs[16][20];
  __shared__ float Ls[16][68];
  int tid = threadIdx.x;
  int i0 = blockIdx.y * 16, j0 = blockIdx.x * 64;
  int lrow = tid >> 2;          // 0..63 L rows
  int lq = tid & 3;
  int xrow = tid & 15;          // 16 X rows (tid<64 loads)
  int xq = (tid >> 4) & 3;
  bool doX = tid < 64;
  bool doSP = (blockIdx.y == 0);
  int tx = tid & 15, ty = tid >> 4;   // ty 0..15 = row, tx*4 = col
  float acc[4] = {};
  float spacc = 0.f;
  for (int k0 = 0; k0 < 784; k0 += 16) {
    float4 lv = *(const float4*)&L[(size_t)(j0 + lrow) * 784 + k0 + lq * 4];
    float4 xv = {0.f, 0.f, 0.f, 0.f};
    if (doX) xv = *(const float4*)&X[(size_t)(i0 + xrow) * 784 + k0 + xq * 4];
    __syncthreads();
    Ls[lq * 4 + 0][lrow] = lv.x; Ls[lq * 4 + 1][lrow] = lv.y;
    Ls[lq * 4 + 2][lrow] = lv.z; Ls[lq * 4 + 3][lrow] = lv.w;
    if (doX) {
      Xs[xq * 4 + 0][xrow] = xv.x; Xs[xq * 4 + 1][xrow] = xv.y;
      Xs[xq * 4 + 2][xrow] = xv.z; Xs[xq * 4 + 3][xrow] = xv.w;
    }
    if (doSP) {
      spacc += fmaxf(lv.x, 0.f) + log1pf(__expf(-fabsf(lv.x)));
      spacc += fmaxf(lv.y, 0.f) + log1pf(__expf(-fabsf(lv.y)));
      spacc += fmaxf(lv.z, 0.f) + log1pf(__expf(-fabsf(lv.z)));
      spacc += fmaxf(lv.w, 0.f) + log1pf(__expf(-fabsf(lv.w)));
    }
    __syncthreads();
#pragma unroll
    for (int k = 0; k < 16; ++k) {
      float a = Xs[k][ty];
      float4 bq = *(const float4*)&Ls[k][tx * 4];
      acc[0] = fmaf(a, bq.x, acc[0]); acc[1] = fmaf(a, bq.y, acc[1]);
      acc[2] = fmaf(a, bq.z, acc[2]); acc[3] = fmaf(a, bq.w, acc[3]);
    }
  }
  float4 o = make_float4(acc[0], acc[1], acc[2], acc[3]);
  *(float4*)&Craw[(size_t)(i0 + ty) * 512 + j0 + tx * 4] = o;
  if (doSP) {
    float q = spacc;
    q += dpp_f<0xB1>(q);
    q += dpp_f<0x4E>(q);
    if (lq == 0) sp[j0 + lrow] = q;
  }
}

// ---------------- prep: rowmax (DPP) + shifted/log2e cost + zero stored + init kl ----------------
__global__ void prep_k(const float* __restrict__ craw, const float* __restrict__ sp,
                       float* __restrict__ D2, float* __restrict__ stored,
                       float* __restrict__ klout) {
  __shared__ float part[4];
  int i = blockIdx.x, tid = threadIdx.x;
  int wid = tid >> 6, lane = tid & 63;
  stored[(size_t)i * 512 + tid] = 0.f;
  stored[(size_t)i * 512 + tid + 256] = 0.f;
  if (i == 0 && tid == 0) klout[0] = 12.476649250079016f;   // 2*log512
  float c0 = craw[(size_t)i * 512 + tid];
  float c1 = craw[(size_t)i * 512 + tid + 256];
  float v0 = c0 - sp[tid];
  float v1 = c1 - sp[tid + 256];
  float wm = wmax64_l63(fmaxf(v0, v1));
  if (lane == 0) part[wid] = wm;
  __syncthreads();
  float m = fmaxf(fmaxf(part[0], part[1]), fmaxf(part[2], part[3]));
  const float L2E = 1.4426950408889634f;
  D2[(size_t)i * 512 + tid] = (m - v0) * L2E;
  D2[(size_t)i * 512 + tid + 256] = (m - v1) * L2E;
}

// ---------------- SAG scan (single wave; R13-proven) ----------------
#define SLD0(ROW) { const float* cp_ = D2 + ((size_t)(unsigned)(ROW) << 9) + jb; \
  s0dA = *(const vf4*)cp_; s0dB = *(const vf4*)(cp_ + 4); \
  const float* tp_ = stored + ((size_t)(unsigned)(ROW) << 9) + jb; \
  s0sA = *(const vf4*)tp_; s0sB = *(const vf4*)(tp_ + 4); }
#define SLD1(ROW) { const float* cp_ = D2 + ((size_t)(unsigned)(ROW) << 9) + jb; \
  s1dA = *(const vf4*)cp_; s1dB = *(const vf4*)(cp_ + 4); \
  const float* tp_ = stored + ((size_t)(unsigned)(ROW) << 9) + jb; \
  s1sA = *(const vf4*)tp_; s1sB = *(const vf4*)(tp_ + 4); }

#define STEP(RR, PFR, DA, DB, SA, SB, LDM, \
             R1,A1,B1, R2,A2,B2, R3,A3,B3, R4,A4,B4, R5,A5,B5, R6,A6,B6, \
             GA, GB) \
{ \
  vf4 d0_ = DA, d1_ = DB, t0_ = SA, t1_ = SB; \
  LDM(PFR); \
  const int r_ = (RR); \
  if (__builtin_expect((r_==(R1)) | (r_==(R2)) | (r_==(R3)) | \
                       (r_==(R4)) | (r_==(R5)) | (r_==(R6)), 0)) { \
    if (r_==(R6)) { t0_ = A6; t1_ = B6; } \
    if (r_==(R5)) { t0_ = A5; t1_ = B5; } \
    if (r_==(R4)) { t0_ = A4; t1_ = B4; } \
    if (r_==(R3)) { t0_ = A3; t1_ = B3; } \
    if (r_==(R2)) { t0_ = A2; t1_ = B2; } \
    if (r_==(R1)) { t0_ = A1; t1_ = B1; } \
  } \
  vf4 u0_ = ssumL - t0_; \
  vf4 u1_ = ssumH - t1_; \
  vf4 a0_ = betaL - d0_; \
  vf4 a1_ = betaH - d1_; \
  vf4 e0_, e1_; \
  e0_.x = __builtin_amdgcn_exp2f(a0_.x); e0_.y = __builtin_amdgcn_exp2f(a0_.y); \
  e0_.z = __builtin_amdgcn_exp2f(a0_.z); e0_.w = __builtin_amdgcn_exp2f(a0_.w); \
  e1_.x = __builtin_amdgcn_exp2f(a1_.x); e1_.y = __builtin_amdgcn_exp2f(a1_.y); \
  e1_.z = __builtin_amdgcn_exp2f(a1_.z); e1_.w = __builtin_amdgcn_exp2f(a1_.w); \
  vf4 es_ = e0_ + e1_; \
  float S_ = wsum64_l63((es_.x + es_.z) + (es_.y + es_.w)); \
  S_ = fmaxf(S_, 1e-35f); \
  float kk_ = C2NL * __builtin_amdgcn_rcpf(S_); \
  vf4 g0_ = e0_ * kk_ + c1l4; \
  vf4 g1_ = e1_ * kk_ + c1l4; \
  ssumL = u0_ + g0_; ssumH = u1_ + g1_; \
  betaL += ssumL; betaH += ssumH; \
  float* wp_ = stored + ((size_t)(unsigned)r_ << 9) + jb; \
  *(vf4*)wp_ = g0_; *(vf4*)(wp_ + 4) = g1_; \
  GA = g0_; GB = g1_; \
}

__global__ void __launch_bounds__(512, 1) sag_k(const float* __restrict__ D2,
                                                const int* __restrict__ idx,
                                                float* __restrict__ stored,
                                                float* __restrict__ beta_out) {
  const int tid = threadIdx.x;
  if (tid >= 64) {
    const vf4* c4 = (const vf4*)D2;
    const vf4* s4 = (const vf4*)stored;
    vf4 acc = {0.f, 0.f, 0.f, 0.f};
    for (int p = tid - 64; p < 65536; p += 448) { acc += c4[p]; acc += s4[p]; }
    float accs = acc.x + acc.y + acc.z + acc.w;
    asm volatile("" :: "v"(accs));
    return;
  }

  const int jb = tid * 8;
  const float C2NL = -0.0028177637f;                 // -(1/512)*log2e
  const vf4 c1l4 = {5.503574e-06f, 5.503574e-06f, 5.503574e-06f, 5.503574e-06f};

  vf4 z4 = {0.f, 0.f, 0.f, 0.f};
  vf4 betaL = z4, betaH = z4, ssumL = z4, ssumH = z4;
  vf4 h1A = z4, h1B = z4, h2A = z4, h2B = z4, h3A = z4, h3B = z4;
  vf4 h4A = z4, h4B = z4, h5A = z4, h5B = z4, h6A = z4, h6B = z4;
  int hr1 = -1, hr2 = -1, hr3 = -1, hr4 = -1, hr5 = -1, hr6 = -1;
  float vsh = 0.f;

  int i0 = RFL(idx[0]), i1 = RFL(idx[1]), i2 = RFL(idx[2]), i3 = RFL(idx[3]);
  int i4 = RFL(idx[4]), i5 = RFL(idx[5]), i6 = RFL(idx[6]), i7 = RFL(idx[7]);

  vf4 s0dA, s0dB, s0sA, s0sB, s1dA, s1dB, s1sA, s1sB;
  SLD0(i0);
  SLD1(i1);

  vf4 g0a, g0b, g1a, g1b, g2a, g2b, g3a, g3b;
  vf4 g4a, g4b, g5a, g5b, g6a, g6b, g7a, g7b;

  for (int t = 0; t < 1000; t += 8) {
    int tb = (t + 8 < 1000) ? (t + 8) : 992;
    int n0 = RFL(idx[tb + 0]), n1 = RFL(idx[tb + 1]);
    int n2 = RFL(idx[tb + 2]), n3 = RFL(idx[tb + 3]);
    int n4 = RFL(idx[tb + 4]), n5 = RFL(idx[tb + 5]);
    int n6 = RFL(idx[tb + 6]), n7 = RFL(idx[tb + 7]);

    STEP(i0, i2, s0dA, s0dB, s0sA, s0sB, SLD0,
         hr1,h1A,h1B, hr2,h2A,h2B, hr3,h3A,h3B, hr4,h4A,h4B, hr5,h5A,h5B, hr6,h6A,h6B,
         g0a, g0b)
    STEP(i1, i3, s1dA, s1dB, s1sA, s1sB, SLD1,
         i0,g0a,g0b, hr1,h1A,h1B, hr2,h2A,h2B, hr3,h3A,h3B, hr4,h4A,h4B, hr5,h5A,h5B,
         g1a, g1b)
    STEP(i2, i4, s0dA, s0dB, s0sA, s0sB, SLD0,
         i1,g1a,g1b, i0,g0a,g0b, hr1,h1A,h1B, hr2,h2A,h2B, hr3,h3A,h3B, hr4,h4A,h4B,
         g2a, g2b)
    STEP(i3, i5, s1dA, s1dB, s1sA, s1sB, SLD1,
         i2,g2a,g2b, i1,g1a,g1b, i0,g0a,g0b, hr1,h1A,h1B, hr2,h2A,h2B, hr3,h3A,h3B,
         g3a, g3b)
    STEP(i4, i6, s0dA, s0dB, s0sA, s0sB, SLD0,
         i3,g3a,g3b, i2,g2a,g2b, i1,g1a,g1b, i0,g0a,g0b, hr1,h1A,h1B, hr2,h2A,h2B,
         g4a, g4b)
    STEP(i5, i7, s1dA, s1dB, s1sA, s1sB, SLD1,
         i4,g4a,g4b, i3,g3a,g3b, i2,g2a,g2b, i1,g1a,g1b, i0,g0a,g0b, hr1,h1A,h1B,
         g5a, g5b)
    STEP(i6, n0, s0dA, s0dB, s0sA, s0sB, SLD0,
         i5,g5a,g5b, i4,g4a,g4b, i3,g3a,g3b, i2,g2a,g2b, i1,g1a,g1b, i0,g0a,g0b,
         g6a, g6b)
    STEP(i7, n1, s1dA, s1dB, s1sA, s1sB, SLD1,
         i6,g6a,g6b, i5,g5a,g5b, i4,g4a,g4b, i3,g3a,g3b, i2,g2a,g2b, i1,g1a,g1b,
         g7a, g7b)

    {
      vf4 qm;
      qm.x = fmaxf(betaL.x, betaH.x); qm.y = fmaxf(betaL.y, betaH.y);
      qm.z = fmaxf(betaL.z, betaH.z); qm.w = fmaxf(betaL.w, betaH.w);
      float lm = fmaxf(fmaxf(qm.x, qm.y), fmaxf(qm.z, qm.w));
      float dm = wmax64_l63(lm);
      betaL = betaL - dm; betaH = betaH - dm;
      vsh += dm;
    }

    hr1 = i7; h1A = g7a; h1B = g7b;
    hr2 = i6; h2A = g6a; h2B = g6b;
    hr3 = i5; h3A = g5a; h3B = g5b;
    hr4 = i4; h4A = g4a; h4B = g4b;
    hr5 = i3; h5A = g3a; h5B = g3b;
    hr6 = i2; h6A = g2a; h6B = g2b;
    i0 = n0; i1 = n1; i2 = n2; i3 = n3;
    i4 = n4; i5 = n5; i6 = n6; i7 = n7;
  }

  const float LN2 = 0.6931471805599453f;
  vf4 oL = (betaL + vsh) * LN2;
  vf4 oH = (betaH + vsh) * LN2;
  *(vf4*)(beta_out + jb) = oL;
  *(vf4*)(beta_out + jb + 4) = oH;
}

// ---------------- plan recovery + C output + entropy + kl atomic ----------------
__global__ void p_k(const float* __restrict__ craw, const float* __restrict__ sp,
                    const float* __restrict__ beta, float* __restrict__ P,
                    float* __restrict__ Cout, float* __restrict__ klout) {
  __shared__ float part[12];
  int i = blockIdx.x, tid = threadIdx.x;
  int wid = tid >> 6, lane = tid & 63;
  float c0 = craw[(size_t)i * 512 + tid];
  float c1 = craw[(size_t)i * 512 + tid + 256];
  float sp0 = sp[tid], sp1 = sp[tid + 256];
  float u0 = (beta[tid] - sp0) + c0;
  float u1 = (beta[tid + 256] - sp1) + c1;
  Cout[(size_t)i * 512 + tid] = sp0 - c0;
  Cout[(size_t)i * 512 + tid + 256] = sp1 - c1;
  float wm = wmax64_l63(fmaxf(u0, u1));
  if (lane == 0) part[wid] = wm;
  __syncthreads();
  float m = fmaxf(fmaxf(part[0], part[1]), fmaxf(part[2], part[3]));
  float e0 = __expf(u0 - m), e1 = __expf(u1 - m);
  float ws = wsum64_l63(e0 + e1);
  if (lane == 0) part[4 + wid] = ws;
  __syncthreads();
  float S = (part[4] + part[5]) + (part[6] + part[7]);
  float lse = m + logf(S);
  const float log512 = 6.238324625039508f;
  float p0 = __expf(u0 - lse) * (1.0f / 512.0f);
  float p1 = __expf(u1 - lse) * (1.0f / 512.0f);
  P[(size_t)i * 512 + tid] = p0;
  P[(size_t)i * 512 + tid + 256] = p1;
  float pl = p0 * (u0 - lse - log512) + p1 * (u1 - lse - log512);
  float wp = wsum64_l63(pl);
  if (lane == 0) part[8 + wid] = wp;
  __syncthreads();
  if (tid == 0)
    atomicAdd(klout, (part[8] + part[9]) + (part[10] + part[11]));
}

extern "C" void kernel_launch(void* const* d_in, const int* in_sizes, int n_in,
                              void* d_out, int out_size, void* d_ws, size_t ws_size,
                              hipStream_t stream) {
  const float* x = (const float*)d_in[0];
  const float* z = (const float*)d_in[1];
  const float* fc_w = (const float*)d_in[2];
  const float* fc_b = (const float*)d_in[3];
  const float* ct0_w = (const float*)d_in[4];
  const float* ct0_b = (const float*)d_in[5];
  const float* ct1_w = (const float*)d_in[6];
  const float* ct1_b = (const float*)d_in[7];
  const float* fct_w = (const float*)d_in[8];
  const float* fct_b = (const float*)d_in[9];
  const float* conv_w = (const float*)d_in[10];
  const float* conv_b = (const float*)d_in[11];
  const int* idx = (const int*)d_in[12];

  float* out = (float*)d_out;
  float* Pout = out;               // 512*512
  float* Cout = out + 262144;      // 512*512
  float* klout = out + 524288;     // 1

  float* ws = (float*)d_ws;
  float* h0 = ws;                       // 512*2048   (-> Craw after ct0)
  float* h1 = h0 + 1048576;             // 512*64*49  (-> D2 after ct1)
  float* h2 = h1 + 1605632;             // 512*32*196
  float* h3 = h2 + 3211264;             // 512*32*784
  float* logit = h3 + 12845056;         // 512*784
  float* sp = logit + 401408;           // 512
  float* beta = sp + 512;               // 512
  float* stored = beta + 512;           // 512*512
  float* Craw = h0;
  float* D2 = h1;

  fc_relu_k<<<1024, 256, 0, stream>>>(z, fc_w, fc_b, h0);
  convt_pair_k<128, 64, 4, 7, 2><<<dim3(16, 32), 256, 0, stream>>>(h0, ct0_w, ct0_b, h1);
  convt_pair_k<64, 32, 7, 14, 2><<<dim3(49, 16), 256, 0, stream>>>(h1, ct1_w, ct1_b, h2);
  convt_pair_k<32, 32, 14, 28, 4><<<dim3(196, 8), 256, 0, stream>>>(h2, fct_w, fct_b, h3);
  conv_final_pair_k<<<784, 256, 0, stream>>>(h3, conv_w, conv_b, logit);
  cost_k<<<dim3(8, 32), 256, 0, stream>>>(x, logit, Craw, sp);
  prep_k<<<512, 256, 0, stream>>>(Craw, sp, D2, stored, klout);
  sag_k<<<1, 512, 0, stream>>>(D2, idx, stored, beta);
  p_k<<<512, 256, 0, stream>>>(Craw, sp, beta, Pout, Cout, klout);
}